// Round 10
// baseline (463.035 us; speedup 1.0000x reference)
//
#include <hip/hip_runtime.h>
#include <hip/hip_bf16.h>
#include <hip/hip_fp16.h>

#define N_NODES 50000
#define N_EDGES 500000
#define HEADS 8
#define HID 64
#define HD 512   // HEADS*HID
#define NCLS 10
#define F2S 12   // feat2 row stride (floats), padded 10->12 for f32x4 loads
#define M_PAD 50048  // 391*128
#define YTILES_L1 391
#define F0ROWS 30080  // 235*128
#define F1ROWS 20096  // 157*128

typedef _Float16 f16x8 __attribute__((ext_vector_type(8)));
typedef _Float16 h8v   __attribute__((ext_vector_type(8)));
typedef _Float16 h2v   __attribute__((ext_vector_type(2)));
typedef float    f32x4 __attribute__((ext_vector_type(4)));

#define GLD_LDS16(g, l) __builtin_amdgcn_global_load_lds( \
    (__attribute__((address_space(1))) void*)(g),         \
    (__attribute__((address_space(3))) void*)(l), 16, 0, 0)

// ---------------------------------------------------------------------------
// prep: one launch, grid-strided sections, VECTORIZED (G13).
// Count section records the edge's ticket (atomicAdd return) for the
// atomic-free scatter.
// ---------------------------------------------------------------------------
#define E_N (F0ROWS * 32)    // 8 elems per thread, 256 cols -> 32 chunks
#define F_N (F1ROWS * 16)    // 128 cols -> 16 chunks
#define A_N (512 * 256)
#define B_N (512 * 128)
#define C_N (512 * 64)       // 64 k-chunks of 8, n inner (coalesced reads)
#define D_N 1024
#define W2H_N 640            // W2 [512][10] -> W2hT [10][512] f16, 8 j's/thread
#define PREP_TOTAL (E_N + F_N + A_N + B_N + C_N + D_N + W2H_N + N_EDGES)

__global__ void prep(const float* __restrict__ feat0, const float* __restrict__ feat1,
                     const float* __restrict__ fc0_w, const float* __restrict__ fc0_b,
                     const float* __restrict__ fc1_w, const float* __restrict__ fc1_b,
                     const float* __restrict__ W0, const float* __restrict__ W1,
                     const float* __restrict__ W2, const int* __restrict__ dst,
                     _Float16* __restrict__ f0h, _Float16* __restrict__ f1h,
                     _Float16* __restrict__ Wc0t, _Float16* __restrict__ Wc1t,
                     _Float16* __restrict__ W1t, _Float16* __restrict__ W2hT,
                     float* __restrict__ biasF, int* __restrict__ cnt,
                     int* __restrict__ tick) {
    int idx = blockIdx.x * 256 + threadIdx.x;
    if (idx < E_N) {
        int m = idx >> 5, c = idx & 31;
        h8v v;
        if (m < 30000) {
            f32x4 a = *(const f32x4*)(feat0 + (size_t)m * 256 + c * 8);
            f32x4 b = *(const f32x4*)(feat0 + (size_t)m * 256 + c * 8 + 4);
#pragma unroll
            for (int j = 0; j < 4; j++) { v[j] = (_Float16)a[j]; v[j+4] = (_Float16)b[j]; }
        } else {
#pragma unroll
            for (int j = 0; j < 8; j++) v[j] = (_Float16)0.f;
        }
        *(h8v*)(f0h + (size_t)m * 256 + c * 8) = v;
        return;
    }
    idx -= E_N;
    if (idx < F_N) {
        int m = idx >> 4, c = idx & 15;
        h8v v;
        if (m < 20000) {
            f32x4 a = *(const f32x4*)(feat1 + (size_t)m * 128 + c * 8);
            f32x4 b = *(const f32x4*)(feat1 + (size_t)m * 128 + c * 8 + 4);
#pragma unroll
            for (int j = 0; j < 4; j++) { v[j] = (_Float16)a[j]; v[j+4] = (_Float16)b[j]; }
        } else {
#pragma unroll
            for (int j = 0; j < 8; j++) v[j] = (_Float16)0.f;
        }
        *(h8v*)(f1h + (size_t)m * 128 + c * 8) = v;
        return;
    }
    idx -= F_N;
    if (idx < A_N) {     // idx = k*512 + n, k<256
        int k = idx >> 9, n = idx & 511;
        float s = 0.f;
#pragma unroll 8
        for (int j = 0; j < 64; j++) s += fc0_w[k * 64 + j] * W0[j * 512 + n];
        Wc0t[n * 256 + k] = (_Float16)s;
        return;
    }
    idx -= A_N;
    if (idx < B_N) {     // idx = k*512 + n, k<128
        int k = idx >> 9, n = idx & 511;
        float s = 0.f;
#pragma unroll 8
        for (int j = 0; j < 64; j++) s += fc1_w[k * 64 + j] * W0[j * 512 + n];
        Wc1t[n * 128 + k] = (_Float16)s;
        return;
    }
    idx -= B_N;
    if (idx < C_N) {     // read 8 rows of W1 coalesced, 16B write
        int kc = idx >> 9, n = idx & 511;
        h8v v;
#pragma unroll
        for (int j = 0; j < 8; j++) v[j] = (_Float16)W1[(size_t)(kc * 8 + j) * 512 + n];
        *(h8v*)(W1t + (size_t)n * 512 + kc * 8) = v;
        return;
    }
    idx -= C_N;
    if (idx < D_N) {     // idx = t*512 + n
        int t = idx >> 9, n = idx & 511;
        const float* fb = t ? fc1_b : fc0_b;
        float s = 0.f;
#pragma unroll 8
        for (int j = 0; j < 64; j++) s += fb[j] * W0[j * 512 + n];
        biasF[t * 512 + n] = s;
        return;
    }
    idx -= D_N;
    if (idx < W2H_N) {   // W2hT[c][j0..j0+7] = f16(W2[j][c]), class-major
        int c = idx >> 6, j0 = (idx & 63) * 8;
        h8v v;
#pragma unroll
        for (int t = 0; t < 8; t++) v[t] = (_Float16)W2[(size_t)(j0 + t) * NCLS + c];
        *(h8v*)(W2hT + (size_t)c * 512 + j0) = v;
        return;
    }
    idx -= W2H_N;
    if (idx < N_EDGES) tick[idx] = atomicAdd(&cnt[dst[idx]], 1);
}

// ---------------------------------------------------------------------------
// CSR scan: parallel 3-kernel scan (proven)
// ---------------------------------------------------------------------------
#define NBLK_SCAN 196  // ceil(50000/256)

__global__ void scan_part(const int* __restrict__ cnt, int* __restrict__ part) {
    __shared__ int s[256];
    int i = blockIdx.x * 256 + threadIdx.x;
    s[threadIdx.x] = (i < N_NODES) ? cnt[i] : 0;
    __syncthreads();
    for (int off = 128; off; off >>= 1) {
        if (threadIdx.x < off) s[threadIdx.x] += s[threadIdx.x + off];
        __syncthreads();
    }
    if (threadIdx.x == 0) part[blockIdx.x] = s[0];
}

__global__ void scan_offs(int* __restrict__ part) {
    __shared__ int s[256];
    int tid = threadIdx.x;
    int v = (tid < NBLK_SCAN) ? part[tid] : 0;
    s[tid] = v;
    __syncthreads();
    for (int off = 1; off < 256; off <<= 1) {
        int x = (tid >= off) ? s[tid - off] : 0;
        __syncthreads();
        s[tid] += x;
        __syncthreads();
    }
    if (tid < NBLK_SCAN) part[tid] = s[tid] - v;  // exclusive
}

__global__ void scan_apply(const int* __restrict__ cnt, const int* __restrict__ part,
                           int* __restrict__ rp) {
    __shared__ int s[256];
    int tid = threadIdx.x;
    int i = blockIdx.x * 256 + tid;
    int v = (i < N_NODES) ? cnt[i] : 0;
    s[tid] = v;
    __syncthreads();
    for (int off = 1; off < 256; off <<= 1) {
        int x = (tid >= off) ? s[tid - off] : 0;
        __syncthreads();
        s[tid] += x;
        __syncthreads();
    }
    if (i < N_NODES) rp[i] = s[tid] - v + part[blockIdx.x];
    if (i == 0) rp[N_NODES] = N_EDGES;
}

// ---------------------------------------------------------------------------
// GEMM tile body: 128x256 tile, 8 waves, BK=64 (was 32), XOR-8 swizzle.
// BK=64 halves the K-iteration count and therefore the per-iteration
// vmcnt(0)+lgkmcnt(0) barrier drains (the m97-structure's documented ~20%
// structural stall). LDS 48KB/block -> 3 blocks/CU (was 4).
// Swizzle: row=128B (8 chunks of 16B); LDS chunk-pos cp holds global chunk
// cp ^ (row&7). Read step s wants global chunk s*4+quad -> cp=(s*4+quad)^(r&7).
// Banks: row stride 128B = bank-neutral; 8 chunks x 4 banks cover all 32.
// ---------------------------------------------------------------------------
__device__ __forceinline__ void gemm_tile(
        const _Float16* __restrict__ A, const _Float16* __restrict__ Bt,
        _Float16* __restrict__ Cb, const float* __restrict__ al,
        const float* __restrict__ ar, const float* __restrict__ cbias,
        float* __restrict__ el, float* __restrict__ er,
        int M, int K, int row_off, int ytiles, int bid,
        _Float16* Asl, _Float16* Bsl) {
    int k8 = bid & 7, jj = bid >> 3;
    int y = k8 + 8 * (jj >> 1);
    if (y >= ytiles) return;
    int m0 = y * 128;
    int n0 = (jj & 1) * 256;
    int t = threadIdx.x;
    int lane = t & 63;
    int w = t >> 6;
    int wm = (w & 1) * 64, wn = (w >> 1) * 64;
    int l15 = lane & 15, quad = lane >> 4;
    f32x4 acc[4][4];
#pragma unroll
    for (int i = 0; i < 4; i++)
#pragma unroll
        for (int j = 0; j < 4; j++) acc[i][j] = (f32x4){0.f, 0.f, 0.f, 0.f};

    // staging offsets: A = 16KB (2 x 8KB passes), B = 32KB (4 passes)
    int fb0 = t * 16;
    int rowA0 = fb0 >> 7,           kgA0 = ((fb0 >> 4) & 7) ^ (rowA0 & 7);
    int fbA1 = fb0 + 8192;
    int rowA1 = fbA1 >> 7,          kgA1 = ((fbA1 >> 4) & 7) ^ (rowA1 & 7);
    int fbB0 = fb0;
    int rowB0 = fbB0 >> 7,          kgB0 = ((fbB0 >> 4) & 7) ^ (rowB0 & 7);
    int fbB1 = fb0 + 8192;
    int rowB1 = fbB1 >> 7,          kgB1 = ((fbB1 >> 4) & 7) ^ (rowB1 & 7);
    int fbB2 = fb0 + 16384;
    int rowB2 = fbB2 >> 7,          kgB2 = ((fbB2 >> 4) & 7) ^ (rowB2 & 7);
    int fbB3 = fb0 + 24576;
    int rowB3 = fbB3 >> 7,          kgB3 = ((fbB3 >> 4) & 7) ^ (rowB3 & 7);

    for (int k0 = 0; k0 < K; k0 += 64) {
        GLD_LDS16(A + (size_t)(m0 + rowA0) * K + k0 + kgA0 * 8, (char*)Asl + fb0);
        GLD_LDS16(A + (size_t)(m0 + rowA1) * K + k0 + kgA1 * 8, (char*)Asl + fbA1);
        GLD_LDS16(Bt + (size_t)(n0 + rowB0) * K + k0 + kgB0 * 8, (char*)Bsl + fbB0);
        GLD_LDS16(Bt + (size_t)(n0 + rowB1) * K + k0 + kgB1 * 8, (char*)Bsl + fbB1);
        GLD_LDS16(Bt + (size_t)(n0 + rowB2) * K + k0 + kgB2 * 8, (char*)Bsl + fbB2);
        GLD_LDS16(Bt + (size_t)(n0 + rowB3) * K + k0 + kgB3 * 8, (char*)Bsl + fbB3);
        __syncthreads();
#pragma unroll
        for (int s = 0; s < 2; s++) {
            f16x8 af[4], bfr[4];
#pragma unroll
            for (int i = 0; i < 4; i++) {
                int r = wm + i * 16 + l15;
                int cp = (s * 4 + quad) ^ (r & 7);
                af[i] = *(const f16x8*)(Asl + r * 64 + cp * 8);
            }
#pragma unroll
            for (int j = 0; j < 4; j++) {
                int r = wn + j * 16 + l15;
                int cp = (s * 4 + quad) ^ (r & 7);
                bfr[j] = *(const f16x8*)(Bsl + r * 64 + cp * 8);
            }
#pragma unroll
            for (int i = 0; i < 4; i++)
#pragma unroll
                for (int j = 0; j < 4; j++)
                    acc[i][j] = __builtin_amdgcn_mfma_f32_16x16x32_f16(af[i], bfr[j], acc[i][j], 0, 0, 0);
        }
        __syncthreads();
    }
    float cb[4];
#pragma unroll
    for (int j = 0; j < 4; j++)
        cb[j] = cbias ? cbias[n0 + wn + j * 16 + l15] : 0.f;
    // C/D layout: col = l15, row = quad*4 + reg  [m89/m91 verified]
#pragma unroll
    for (int i = 0; i < 4; i++) {
        int rbase = m0 + wm + i * 16 + quad * 4;
#pragma unroll
        for (int j = 0; j < 4; j++) {
            int col = n0 + wn + j * 16 + l15;
#pragma unroll
            for (int r = 0; r < 4; r++) {
                int row = rbase + r;
                if (row < M)
                    Cb[(size_t)(row_off + row) * HD + col] = (_Float16)(acc[i][j][r] + cb[j]);
            }
        }
    }
    int h = (n0 + wn) >> 6;
    float alv[4], arv[4];
#pragma unroll
    for (int j = 0; j < 4; j++) {
        alv[j] = al[h * 64 + j * 16 + l15];
        arv[j] = ar[h * 64 + j * 16 + l15];
    }
#pragma unroll
    for (int i = 0; i < 4; i++) {
#pragma unroll
        for (int r = 0; r < 4; r++) {
            float sl = 0.f, sr = 0.f;
#pragma unroll
            for (int j = 0; j < 4; j++) {
                float v = acc[i][j][r] + cb[j];
                sl += v * alv[j]; sr += v * arv[j];
            }
#pragma unroll
            for (int mk = 1; mk < 16; mk <<= 1) {
                sl += __shfl_xor(sl, mk);
                sr += __shfl_xor(sr, mk);
            }
            int row = m0 + wm + i * 16 + quad * 4 + r;
            if (l15 == 0 && row < M) {
                el[(size_t)(row_off + row) * HEADS + h] = sl;
                er[(size_t)(row_off + row) * HEADS + h] = sr;
            }
        }
    }
}

// ---------------------------------------------------------------------------
// Heterogeneous fused launch: scatter blocks + L0a GEMM blocks + L0b blocks.
// Scatter is atomic-free (ticket from prep).
// ---------------------------------------------------------------------------
#define SCAT_BLKS 128
#define G0A_BLKS (8 * 2 * ((235 + 7) / 8))  // 480
#define G0B_BLKS (8 * 2 * ((157 + 7) / 8))  // 320

__global__ __launch_bounds__(512) void scatter_gemm0(
        const int* __restrict__ src, const int* __restrict__ dst,
        const int* __restrict__ rp, const int* __restrict__ tick,
        int* __restrict__ srcs,
        const _Float16* __restrict__ f0h, const _Float16* __restrict__ Wc0t,
        const _Float16* __restrict__ f1h, const _Float16* __restrict__ Wc1t,
        _Float16* __restrict__ featA, const float* __restrict__ al0,
        const float* __restrict__ ar0, const float* __restrict__ biasF,
        float* __restrict__ el, float* __restrict__ er) {
    __shared__ _Float16 Asl[128 * 64];
    __shared__ _Float16 Bsl[256 * 64];
    int bid = blockIdx.x;
    if (bid < SCAT_BLKS) {
        for (int t = bid * 512 + threadIdx.x; t < N_EDGES; t += SCAT_BLKS * 512) {
            srcs[rp[dst[t]] + tick[t]] = src[t];
        }
        return;
    }
    bid -= SCAT_BLKS;
    if (bid < G0A_BLKS) {
        gemm_tile(f0h, Wc0t, featA, al0, ar0, biasF, el, er,
                  30000, 256, 0, 235, bid, Asl, Bsl);
        return;
    }
    bid -= G0A_BLKS;
    gemm_tile(f1h, Wc1t, featA, al0, ar0, biasF + 512, el, er,
              20000, 128, 30000, 157, bid, Asl, Bsl);
}

// ---------------------------------------------------------------------------
// Standalone wide GEMM (layer 1)
// ---------------------------------------------------------------------------
__global__ __launch_bounds__(512) void gemm_mfma_wide(const _Float16* __restrict__ A,
                                                      const _Float16* __restrict__ Bt,
                                                      _Float16* __restrict__ Cb,
                                                      const float* __restrict__ al,
                                                      const float* __restrict__ ar,
                                                      float* __restrict__ el,
                                                      float* __restrict__ er,
                                                      int M, int K, int ytiles) {
    __shared__ _Float16 Asl[128 * 64];
    __shared__ _Float16 Bsl[256 * 64];
    gemm_tile(A, Bt, Cb, al, ar, nullptr, el, er, M, K, 0, ytiles,
              blockIdx.x, Asl, Bsl);
}

// ---------------------------------------------------------------------------
// Fused edge softmax + aggregation, one wave per block (proven structure,
// ~88 us = random-gather memory-path floor per r2-r4 ablations).
// ---------------------------------------------------------------------------
__global__ __launch_bounds__(64) void attn_agg(
        const int* __restrict__ rp, const int* __restrict__ srcs,
        const float* __restrict__ el, const float* __restrict__ er,
        const _Float16* __restrict__ feat, const float* __restrict__ bias,
        _Float16* __restrict__ out) {
    __shared__ float aS[592];   // [0..575] alpha (p*9+h), [576..583] inv, [584..591] m
    __shared__ int   sS[64];
    int lane = threadIdx.x;
    int n    = blockIdx.x;
    int s0 = rp[n], s1 = rp[n + 1];
    int deg = s1 - s0;
    float er8[8];
    {
        f32x4 a = *(const f32x4*)(er + (size_t)n * 8);
        f32x4 b = *(const f32x4*)(er + (size_t)n * 8 + 4);
        er8[0]=a[0]; er8[1]=a[1]; er8[2]=a[2]; er8[3]=a[3];
        er8[4]=b[0]; er8[5]=b[1]; er8[6]=b[2]; er8[7]=b[3];
    }
    bool fast = (deg <= 64);
    if (fast) {
        bool act = lane < deg;
        int sp = act ? srcs[s0 + lane] : 0;
        sS[lane] = sp;
        f32x4 ea = {0.f,0.f,0.f,0.f}, eb = {0.f,0.f,0.f,0.f};
        if (act) {
            ea = *(const f32x4*)(el + (size_t)sp * 8);
            eb = *(const f32x4*)(el + (size_t)sp * 8 + 4);
        }
        float e8[8] = {ea[0],ea[1],ea[2],ea[3],eb[0],eb[1],eb[2],eb[3]};
#pragma unroll
        for (int h = 0; h < 8; h++) {
            float e = e8[h] + er8[h];
            e = e > 0.f ? e : 0.2f * e;
            e8[h] = act ? e : -1e30f;
        }
#pragma unroll
        for (int h = 0; h < 8; h++) {
            float mm = e8[h];
#pragma unroll
            for (int mk = 1; mk < 64; mk <<= 1) mm = fmaxf(mm, __shfl_xor(mm, mk));
            float pv = act ? __expf(e8[h] - mm) : 0.f;
            float ss = pv;
#pragma unroll
            for (int mk = 1; mk < 64; mk <<= 1) ss += __shfl_xor(ss, mk);
            aS[lane * 9 + h] = pv * (1.f / fmaxf(ss, 1e-9f));  // pre-scaled alpha
        }
    } else {
        float m8[8], s8[8];
#pragma unroll
        for (int h = 0; h < 8; h++) { m8[h] = -1e30f; s8[h] = 0.f; }
        for (int base = s0; base < s1; base += 64) {
            bool act = base + lane < s1;
            int sp = act ? srcs[base + lane] : 0;
            f32x4 ea = {0.f,0.f,0.f,0.f}, eb = {0.f,0.f,0.f,0.f};
            if (act) {
                ea = *(const f32x4*)(el + (size_t)sp * 8);
                eb = *(const f32x4*)(el + (size_t)sp * 8 + 4);
            }
            float ev[8] = {ea[0],ea[1],ea[2],ea[3],eb[0],eb[1],eb[2],eb[3]};
#pragma unroll
            for (int h = 0; h < 8; h++) {
                float e = ev[h] + er8[h];
                e = e > 0.f ? e : 0.2f * e;
                e = act ? e : -1e30f;
                float cm = e;
#pragma unroll
                for (int mk = 1; mk < 64; mk <<= 1) cm = fmaxf(cm, __shfl_xor(cm, mk));
                float nm = fmaxf(m8[h], cm);
                float pv = act ? __expf(e - nm) : 0.f;
#pragma unroll
                for (int mk = 1; mk < 64; mk <<= 1) pv += __shfl_xor(pv, mk);
                s8[h] = s8[h] * __expf(m8[h] - nm) + pv;
                m8[h] = nm;
            }
        }
        if (lane == 0) {
#pragma unroll
            for (int h = 0; h < 8; h++) {
                aS[576 + h] = 1.f / fmaxf(s8[h], 1e-9f);
                aS[584 + h] = m8[h];
            }
        }
    }
    // wave-private LDS handoff (lockstep wave + compiler lgkmcnt ordering)
    __builtin_amdgcn_wave_barrier();
    int hh = lane >> 3, d0 = (lane & 7) * 8;   // lane*8 = hh*64 + d0
    h8v z = {(_Float16)0, (_Float16)0, (_Float16)0, (_Float16)0,
             (_Float16)0, (_Float16)0, (_Float16)0, (_Float16)0};
    h8v acc0 = z, acc1 = z, acc2 = z, acc3 = z;
    const _Float16* colbase = feat + hh * 64 + d0;
    if (fast) {
        int p = 0;
        for (; p + 4 <= deg; p += 4) {
            int spa = sS[p],     spb = sS[p + 1];
            int spc = sS[p + 2], spd = sS[p + 3];
            _Float16 aa = (_Float16)aS[p * 9 + hh];
            _Float16 ab = (_Float16)aS[(p + 1) * 9 + hh];
            _Float16 ac = (_Float16)aS[(p + 2) * 9 + hh];
            _Float16 ad = (_Float16)aS[(p + 3) * 9 + hh];
            h8v fa = *(const h8v*)(colbase + (size_t)spa * HD);
            h8v fb = *(const h8v*)(colbase + (size_t)spb * HD);
            h8v fc = *(const h8v*)(colbase + (size_t)spc * HD);
            h8v fd = *(const h8v*)(colbase + (size_t)spd * HD);
            h8v a8a = {aa, aa, aa, aa, aa, aa, aa, aa};
            h8v a8b = {ab, ab, ab, ab, ab, ab, ab, ab};
            h8v a8c = {ac, ac, ac, ac, ac, ac, ac, ac};
            h8v a8d = {ad, ad, ad, ad, ad, ad, ad, ad};
            acc0 += a8a * fa;
            acc1 += a8b * fb;
            acc2 += a8c * fc;
            acc3 += a8d * fd;
        }
        for (; p < deg; p++) {
            int sp = sS[p];
            _Float16 ah = (_Float16)aS[p * 9 + hh];
            h8v a8 = {ah, ah, ah, ah, ah, ah, ah, ah};
            h8v f = *(const h8v*)(colbase + (size_t)sp * HD);
            acc0 += a8 * f;
        }
    } else {
        float inv_l = aS[576 + hh];
        float m_l   = aS[584 + hh];
        float ern_l = er[(size_t)n * 8 + hh];
        for (int p = s0; p < s1; p++) {
            int sp = srcs[p];
            float e = el[(size_t)sp * 8 + hh] + ern_l;
            e = e > 0.f ? e : 0.2f * e;
            _Float16 ah = (_Float16)(__expf(e - m_l) * inv_l);
            h8v a8 = {ah, ah, ah, ah, ah, ah, ah, ah};
            h8v f = *(const h8v*)(colbase + (size_t)sp * HD);
            acc0 += a8 * f;
        }
    }
    acc0 += acc1; acc2 += acc3; acc0 += acc2;
    float4 b0v = *(const float4*)(bias + lane * 8);
    float4 b1v = *(const float4*)(bias + lane * 8 + 4);
    float bb[8] = {b0v.x,b0v.y,b0v.z,b0v.w,b1v.x,b1v.y,b1v.z,b1v.w};
    h8v o;
#pragma unroll
    for (int j = 0; j < 8; j++) {
        float x = (float)acc0[j] + bb[j];
        x = x > 0.f ? x : __expf(x) - 1.f;
        o[j] = (_Float16)x;
    }
    *(h8v*)(out + (size_t)n * HD + lane * 8) = o;
}

// ---------------------------------------------------------------------------
// Layer-2 variant: softmax+aggregation + fused [512->10] W2 projection.
// ---------------------------------------------------------------------------
__global__ __launch_bounds__(64) void attn_agg_l2(
        const int* __restrict__ rp, const int* __restrict__ srcs,
        const float* __restrict__ el, const float* __restrict__ er,
        const _Float16* __restrict__ feat, const float* __restrict__ bias,
        const _Float16* __restrict__ W2hT, const float* __restrict__ al2,
        const float* __restrict__ ar2, float* __restrict__ feat2,
        float* __restrict__ el2, float* __restrict__ er2) {
    __shared__ float aS[592];
    __shared__ int   sS[64];
    int lane = threadIdx.x;
    int n    = blockIdx.x;
    int s0 = rp[n], s1 = rp[n + 1];
    int deg = s1 - s0;
    float er8[8];
    {
        f32x4 a = *(const f32x4*)(er + (size_t)n * 8);
        f32x4 b = *(const f32x4*)(er + (size_t)n * 8 + 4);
        er8[0]=a[0]; er8[1]=a[1]; er8[2]=a[2]; er8[3]=a[3];
        er8[4]=b[0]; er8[5]=b[1]; er8[6]=b[2]; er8[7]=b[3];
    }
    bool fast = (deg <= 64);
    if (fast) {
        bool act = lane < deg;
        int sp = act ? srcs[s0 + lane] : 0;
        sS[lane] = sp;
        f32x4 ea = {0.f,0.f,0.f,0.f}, eb = {0.f,0.f,0.f,0.f};
        if (act) {
            ea = *(const f32x4*)(el + (size_t)sp * 8);
            eb = *(const f32x4*)(el + (size_t)sp * 8 + 4);
        }
        float e8[8] = {ea[0],ea[1],ea[2],ea[3],eb[0],eb[1],eb[2],eb[3]};
#pragma unroll
        for (int h = 0; h < 8; h++) {
            float e = e8[h] + er8[h];
            e = e > 0.f ? e : 0.2f * e;
            e8[h] = act ? e : -1e30f;
        }
#pragma unroll
        for (int h = 0; h < 8; h++) {
            float mm = e8[h];
#pragma unroll
            for (int mk = 1; mk < 64; mk <<= 1) mm = fmaxf(mm, __shfl_xor(mm, mk));
            float pv = act ? __expf(e8[h] - mm) : 0.f;
            float ss = pv;
#pragma unroll
            for (int mk = 1; mk < 64; mk <<= 1) ss += __shfl_xor(ss, mk);
            aS[lane * 9 + h] = pv * (1.f / fmaxf(ss, 1e-9f));
        }
    } else {
        float m8[8], s8[8];
#pragma unroll
        for (int h = 0; h < 8; h++) { m8[h] = -1e30f; s8[h] = 0.f; }
        for (int base = s0; base < s1; base += 64) {
            bool act = base + lane < s1;
            int sp = act ? srcs[base + lane] : 0;
            f32x4 ea = {0.f,0.f,0.f,0.f}, eb = {0.f,0.f,0.f,0.f};
            if (act) {
                ea = *(const f32x4*)(el + (size_t)sp * 8);
                eb = *(const f32x4*)(el + (size_t)sp * 8 + 4);
            }
            float ev[8] = {ea[0],ea[1],ea[2],ea[3],eb[0],eb[1],eb[2],eb[3]};
#pragma unroll
            for (int h = 0; h < 8; h++) {
                float e = ev[h] + er8[h];
                e = e > 0.f ? e : 0.2f * e;
                e = act ? e : -1e30f;
                float cm = e;
#pragma unroll
                for (int mk = 1; mk < 64; mk <<= 1) cm = fmaxf(cm, __shfl_xor(cm, mk));
                float nm = fmaxf(m8[h], cm);
                float pv = act ? __expf(e - nm) : 0.f;
#pragma unroll
                for (int mk = 1; mk < 64; mk <<= 1) pv += __shfl_xor(pv, mk);
                s8[h] = s8[h] * __expf(m8[h] - nm) + pv;
                m8[h] = nm;
            }
        }
        if (lane == 0) {
#pragma unroll
            for (int h = 0; h < 8; h++) {
                aS[576 + h] = 1.f / fmaxf(s8[h], 1e-9f);
                aS[584 + h] = m8[h];
            }
        }
    }
    __builtin_amdgcn_wave_barrier();
    int hh = lane >> 3, d0 = (lane & 7) * 8;
    h8v z = {(_Float16)0, (_Float16)0, (_Float16)0, (_Float16)0,
             (_Float16)0, (_Float16)0, (_Float16)0, (_Float16)0};
    h8v acc0 = z, acc1 = z, acc2 = z, acc3 = z;
    const _Float16* colbase = feat + hh * 64 + d0;
    if (fast) {
        int p = 0;
        for (; p + 4 <= deg; p += 4) {
            int spa = sS[p],     spb = sS[p + 1];
            int spc = sS[p + 2], spd = sS[p + 3];
            _Float16 aa = (_Float16)aS[p * 9 + hh];
            _Float16 ab = (_Float16)aS[(p + 1) * 9 + hh];
            _Float16 ac = (_Float16)aS[(p + 2) * 9 + hh];
            _Float16 ad = (_Float16)aS[(p + 3) * 9 + hh];
            h8v fa = *(const h8v*)(colbase + (size_t)spa * HD);
            h8v fb = *(const h8v*)(colbase + (size_t)spb * HD);
            h8v fc = *(const h8v*)(colbase + (size_t)spc * HD);
            h8v fd = *(const h8v*)(colbase + (size_t)spd * HD);
            h8v a8a = {aa, aa, aa, aa, aa, aa, aa, aa};
            h8v a8b = {ab, ab, ab, ab, ab, ab, ab, ab};
            h8v a8c = {ac, ac, ac, ac, ac, ac, ac, ac};
            h8v a8d = {ad, ad, ad, ad, ad, ad, ad, ad};
            acc0 += a8a * fa;
            acc1 += a8b * fb;
            acc2 += a8c * fc;
            acc3 += a8d * fd;
        }
        for (; p < deg; p++) {
            int sp = sS[p];
            _Float16 ah = (_Float16)aS[p * 9 + hh];
            h8v a8 = {ah, ah, ah, ah, ah, ah, ah, ah};
            h8v f = *(const h8v*)(colbase + (size_t)sp * HD);
            acc0 += a8 * f;
        }
    } else {
        float inv_l = aS[576 + hh];
        float m_l   = aS[584 + hh];
        float ern_l = er[(size_t)n * 8 + hh];
        for (int p = s0; p < s1; p++) {
            int sp = srcs[p];
            float e = el[(size_t)sp * 8 + hh] + ern_l;
            e = e > 0.f ? e : 0.2f * e;
            _Float16 ah = (_Float16)(__expf(e - m_l) * inv_l);
            h8v a8 = {ah, ah, ah, ah, ah, ah, ah, ah};
            h8v f = *(const h8v*)(colbase + (size_t)sp * HD);
            acc0 += a8 * f;
        }
    }
    acc0 += acc1; acc2 += acc3; acc0 += acc2;
    float4 b0v = *(const float4*)(bias + lane * 8);
    float4 b1v = *(const float4*)(bias + lane * 8 + 4);
    float bb[8] = {b0v.x,b0v.y,b0v.z,b0v.w,b1v.x,b1v.y,b1v.z,b1v.w};
    float x[8];
#pragma unroll
    for (int j = 0; j < 8; j++) {
        float v = (float)acc0[j] + bb[j];
        x[j] = v > 0.f ? v : __expf(v) - 1.f;     // ELU in f32 (layer-1 act)
    }
    // fused [512->10] projection: lane owns j-cols lane*8..lane*8+7.
    float s[NCLS];
    const _Float16* w2base = W2hT + lane * 8;
#if __has_builtin(__builtin_amdgcn_fdot2)
    h2v xh[4];
#pragma unroll
    for (int j = 0; j < 4; j++)
        xh[j] = (h2v){(_Float16)x[2 * j], (_Float16)x[2 * j + 1]};
#pragma unroll
    for (int c = 0; c < NCLS; c++) {
        h8v w = *(const h8v*)(w2base + (size_t)c * 512);
        float acc = 0.f;
#pragma unroll
        for (int jp = 0; jp < 4; jp++) {
            h2v wp = (h2v){w[2 * jp], w[2 * jp + 1]};
            acc = __builtin_amdgcn_fdot2(xh[jp], wp, acc, false);
        }
        s[c] = acc;
    }
#else
#pragma unroll
    for (int c = 0; c < NCLS; c++) {
        h8v w = *(const h8v*)(w2base + (size_t)c * 512);
        float acc = 0.f;
#pragma unroll
        for (int j = 0; j < 8; j++) acc += x[j] * (float)w[j];
        s[c] = acc;
    }
#endif
#pragma unroll
    for (int c = 0; c < NCLS; c++)
#pragma unroll
        for (int mk = 1; mk < 64; mk <<= 1) s[c] += __shfl_xor(s[c], mk);
    if (lane == 0) {
        float e1 = 0.f, e2 = 0.f;
#pragma unroll
        for (int c = 0; c < NCLS; c++) { e1 += s[c] * al2[c]; e2 += s[c] * ar2[c]; }
        el2[n] = e1; er2[n] = e2;
#pragma unroll
        for (int c = 0; c < NCLS; c++) feat2[(size_t)n * F2S + c] = s[c];
    }
}

// ---------------------------------------------------------------------------
// layer 2 fused softmax+aggregation (H=1, D=10), one wave per block.
// feat2 rows padded to stride 12 -> 3x f32x4 vector loads.
// ---------------------------------------------------------------------------
__global__ __launch_bounds__(64) void attn2_agg2(
        const int* __restrict__ rp, const int* __restrict__ srcs,
        const float* __restrict__ el, const float* __restrict__ er,
        const float* __restrict__ feat2, const float* __restrict__ b2,
        float* __restrict__ out) {
    int lane = threadIdx.x;
    int n = blockIdx.x;
    int s0 = rp[n], s1 = rp[n + 1], deg = s1 - s0;
    float ern = er[n];
    float facc[NCLS];
#pragma unroll
    for (int c = 0; c < NCLS; c++) facc[c] = 0.f;
    if (deg <= 64) {
        bool act = lane < deg;
        int sp = act ? srcs[s0 + lane] : 0;
        float e = act ? el[sp] + ern : 0.f;
        e = e > 0.f ? e : 0.2f * e;
        if (!act) e = -1e30f;
        float mm = e;
#pragma unroll
        for (int mk = 1; mk < 64; mk <<= 1) mm = fmaxf(mm, __shfl_xor(mm, mk));
        float pv = act ? __expf(e - mm) : 0.f;
        float ss = pv;
#pragma unroll
        for (int mk = 1; mk < 64; mk <<= 1) ss += __shfl_xor(ss, mk);
        float a = pv / fmaxf(ss, 1e-9f);
        if (act) {
            const float* fr = feat2 + (size_t)sp * F2S;
            f32x4 fa = *(const f32x4*)fr;
            f32x4 fb = *(const f32x4*)(fr + 4);
            f32x4 fc = *(const f32x4*)(fr + 8);
            float fv[NCLS] = {fa[0],fa[1],fa[2],fa[3],fb[0],fb[1],fb[2],fb[3],fc[0],fc[1]};
#pragma unroll
            for (int c = 0; c < NCLS; c++) facc[c] = a * fv[c];
        }
    } else {
        float mm = -1e30f, ssum = 0.f;
        for (int base = s0; base < s1; base += 64) {
            bool act = base + lane < s1;
            int sp = act ? srcs[base + lane] : 0;
            float e = act ? el[sp] + ern : 0.f;
            e = e > 0.f ? e : 0.2f * e;
            if (!act) e = -1e30f;
            float cm = e;
#pragma unroll
            for (int mk = 1; mk < 64; mk <<= 1) cm = fmaxf(cm, __shfl_xor(cm, mk));
            float nm = fmaxf(mm, cm);
            float pv = act ? __expf(e - nm) : 0.f;
#pragma unroll
            for (int mk = 1; mk < 64; mk <<= 1) pv += __shfl_xor(pv, mk);
            ssum = ssum * __expf(mm - nm) + pv;
            mm = nm;
        }
        float inv = 1.f / fmaxf(ssum, 1e-9f);
        for (int base = s0; base < s1; base += 64) {
            bool act = base + lane < s1;
            int sp = act ? srcs[base + lane] : 0;
            float e = act ? el[sp] + ern : 0.f;
            e = e > 0.f ? e : 0.2f * e;
            float a = act ? __expf(e - mm) * inv : 0.f;
            if (act) {
                const float* fr = feat2 + (size_t)sp * F2S;
                f32x4 fa = *(const f32x4*)fr;
                f32x4 fb = *(const f32x4*)(fr + 4);
                f32x4 fc = *(const f32x4*)(fr + 8);
                float fv[NCLS] = {fa[0],fa[1],fa[2],fa[3],fb[0],fb[1],fb[2],fb[3],fc[0],fc[1]};
#pragma unroll
                for (int c = 0; c < NCLS; c++) facc[c] += a * fv[c];
            }
        }
    }
#pragma unroll
    for (int c = 0; c < NCLS; c++)
#pragma unroll
        for (int mk = 1; mk < 64; mk <<= 1) facc[c] += __shfl_xor(facc[c], mk);
    if (lane == 0) {
#pragma unroll
        for (int c = 0; c < NCLS; c++) out[(size_t)n * NCLS + c] = facc[c] + b2[c];
    }
}

// ---------------------------------------------------------------------------
extern "C" void kernel_launch(void* const* d_in, const int* in_sizes, int n_in,
                              void* d_out, int out_size, void* d_ws, size_t ws_size,
                              hipStream_t stream) {
    const float* feat0 = (const float*)d_in[0];
    const float* feat1 = (const float*)d_in[1];
    const float* fc0_w = (const float*)d_in[2];
    const float* fc0_b = (const float*)d_in[3];
    const float* fc1_w = (const float*)d_in[4];
    const float* fc1_b = (const float*)d_in[5];
    const float* W0    = (const float*)d_in[6];
    const float* al0   = (const float*)d_in[7];
    const float* ar0   = (const float*)d_in[8];
    const float* b0    = (const float*)d_in[9];
    const float* W1    = (const float*)d_in[10];
    const float* al1   = (const float*)d_in[11];
    const float* ar1   = (const float*)d_in[12];
    const float* b1    = (const float*)d_in[13];
    const float* W2    = (const float*)d_in[14];
    const float* al2   = (const float*)d_in[15];
    const float* ar2   = (const float*)d_in[16];
    const float* b2    = (const float*)d_in[17];
    const int* eidx    = (const int*)d_in[18];
    const int* src = eidx;
    const int* dst = eidx + N_EDGES;
    float* out = (float*)d_out;

    char* ws = (char*)d_ws;
    size_t off = 0;
    auto alloc = [&](size_t bytes) { size_t o = off; off = (off + bytes + 255) & ~(size_t)255; return o; };

    _Float16* featA = (_Float16*)(ws + alloc((size_t)M_PAD * HD * 2));
    _Float16* aggh  = (_Float16*)(ws + alloc((size_t)M_PAD * HD * 2));
    _Float16* f0h   = (_Float16*)(ws + alloc((size_t)F0ROWS * 256 * 2));
    _Float16* f1h   = (_Float16*)(ws + alloc((size_t)F1ROWS * 128 * 2));
    float*    feat2 = (float*)(ws + alloc((size_t)N_NODES * F2S * 4));
    float*    el    = (float*)(ws + alloc((size_t)N_NODES * HEADS * 4));
    float*    er    = (float*)(ws + alloc((size_t)N_NODES * HEADS * 4));
    float*    el2   = (float*)(ws + alloc((size_t)N_NODES * 4));
    float*    er2   = (float*)(ws + alloc((size_t)N_NODES * 4));
    float*    biasF = (float*)(ws + alloc(1024 * 4));
    int*      cnt   = (int*)  (ws + alloc((size_t)N_NODES * 4));
    int*      rp    = (int*)  (ws + alloc((size_t)(N_NODES + 1) * 4));
    int*      tick  = (int*)  (ws + alloc((size_t)N_EDGES * 4));
    int*      srcs  = (int*)  (ws + alloc((size_t)N_EDGES * 4));
    int*      part  = (int*)  (ws + alloc(1024));
    _Float16* Wc0t  = (_Float16*)(ws + alloc(512 * 256 * 2));
    _Float16* Wc1t  = (_Float16*)(ws + alloc(512 * 128 * 2));
    _Float16* W1t   = (_Float16*)(ws + alloc(512 * 512 * 2));
    _Float16* W2hT  = (_Float16*)(ws + alloc(5120 * 2));

    // --- cnt zero, then prep (weight folds + casts + count/ticket fused) ---
    hipMemsetAsync(cnt, 0, N_NODES * sizeof(int), stream);
    prep<<<(PREP_TOTAL + 255) / 256, 256, 0, stream>>>(
        feat0, feat1, fc0_w, fc0_b, fc1_w, fc1_b, W0, W1, W2, dst,
        f0h, f1h, Wc0t, Wc1t, W1t, W2hT, biasF, cnt, tick);

    // --- CSR scan ---
    scan_part<<<NBLK_SCAN, 256, 0, stream>>>(cnt, part);
    scan_offs<<<1, 256, 0, stream>>>(part);
    scan_apply<<<NBLK_SCAN, 256, 0, stream>>>(cnt, part, rp);

    // --- fused: atomic-free scatter + layer-0 GEMMs (one launch) ---
    scatter_gemm0<<<SCAT_BLKS + G0A_BLKS + G0B_BLKS, 512, 0, stream>>>(
        src, dst, rp, tick, srcs, f0h, Wc0t, f1h, Wc1t, featA, al0, ar0, biasF, el, er);

    attn_agg<<<N_NODES, 64, 0, stream>>>(rp, srcs, el, er, featA, b0, aggh);

    // --- layer 1 ---
    int g1 = 8 * 2 * ((YTILES_L1 + 7) / 8);  // 784
    gemm_mfma_wide<<<g1, 512, 0, stream>>>(aggh, W1t, featA, al1, ar1, el, er,
                                           N_NODES, HD, YTILES_L1);

    // --- layer 1 attn + fused layer-2 projection ---
    attn_agg_l2<<<N_NODES, 64, 0, stream>>>(rp, srcs, el, er, featA, b1,
                                            W2hT, al2, ar2, feat2, el2, er2);

    // --- layer 2 softmax+agg ---
    attn2_agg2<<<N_NODES, 64, 0, stream>>>(rp, srcs, el2, er2, feat2, b2, out);
}

// Round 11
// 454.330 us; speedup vs baseline: 1.0192x; 1.0192x over previous
//
#include <hip/hip_runtime.h>
#include <hip/hip_bf16.h>
#include <hip/hip_fp16.h>

#define N_NODES 50000
#define N_EDGES 500000
#define HEADS 8
#define HID 64
#define HD 512   // HEADS*HID
#define NCLS 10
#define F2S 12   // feat2 row stride (floats), padded 10->12 for f32x4 loads
#define M_PAD 50048  // 391*128
#define YTILES_L1 391
#define F0ROWS 30080  // 235*128
#define F1ROWS 20096  // 157*128

typedef _Float16 f16x8 __attribute__((ext_vector_type(8)));
typedef _Float16 h8v   __attribute__((ext_vector_type(8)));
typedef _Float16 h2v   __attribute__((ext_vector_type(2)));
typedef float    f32x4 __attribute__((ext_vector_type(4)));

#define GLD_LDS16(g, l) __builtin_amdgcn_global_load_lds( \
    (__attribute__((address_space(1))) void*)(g),         \
    (__attribute__((address_space(3))) void*)(l), 16, 0, 0)

// ---------------------------------------------------------------------------
// prep: one launch, grid-strided sections, VECTORIZED (G13).
// Count section records the edge's ticket (atomicAdd return) for the
// atomic-free scatter.
// ---------------------------------------------------------------------------
#define E_N (F0ROWS * 32)    // 8 elems per thread, 256 cols -> 32 chunks
#define F_N (F1ROWS * 16)    // 128 cols -> 16 chunks
#define A_N (512 * 256)
#define B_N (512 * 128)
#define C_N (512 * 64)       // 64 k-chunks of 8, n inner (coalesced reads)
#define D_N 1024
#define W2H_N 640            // W2 [512][10] -> W2hT [10][512] f16, 8 j's/thread
#define PREP_TOTAL (E_N + F_N + A_N + B_N + C_N + D_N + W2H_N + N_EDGES)

__global__ void prep(const float* __restrict__ feat0, const float* __restrict__ feat1,
                     const float* __restrict__ fc0_w, const float* __restrict__ fc0_b,
                     const float* __restrict__ fc1_w, const float* __restrict__ fc1_b,
                     const float* __restrict__ W0, const float* __restrict__ W1,
                     const float* __restrict__ W2, const int* __restrict__ dst,
                     _Float16* __restrict__ f0h, _Float16* __restrict__ f1h,
                     _Float16* __restrict__ Wc0t, _Float16* __restrict__ Wc1t,
                     _Float16* __restrict__ W1t, _Float16* __restrict__ W2hT,
                     float* __restrict__ biasF, int* __restrict__ cnt,
                     int* __restrict__ tick) {
    int idx = blockIdx.x * 256 + threadIdx.x;
    if (idx < E_N) {
        int m = idx >> 5, c = idx & 31;
        h8v v;
        if (m < 30000) {
            f32x4 a = *(const f32x4*)(feat0 + (size_t)m * 256 + c * 8);
            f32x4 b = *(const f32x4*)(feat0 + (size_t)m * 256 + c * 8 + 4);
#pragma unroll
            for (int j = 0; j < 4; j++) { v[j] = (_Float16)a[j]; v[j+4] = (_Float16)b[j]; }
        } else {
#pragma unroll
            for (int j = 0; j < 8; j++) v[j] = (_Float16)0.f;
        }
        *(h8v*)(f0h + (size_t)m * 256 + c * 8) = v;
        return;
    }
    idx -= E_N;
    if (idx < F_N) {
        int m = idx >> 4, c = idx & 15;
        h8v v;
        if (m < 20000) {
            f32x4 a = *(const f32x4*)(feat1 + (size_t)m * 128 + c * 8);
            f32x4 b = *(const f32x4*)(feat1 + (size_t)m * 128 + c * 8 + 4);
#pragma unroll
            for (int j = 0; j < 4; j++) { v[j] = (_Float16)a[j]; v[j+4] = (_Float16)b[j]; }
        } else {
#pragma unroll
            for (int j = 0; j < 8; j++) v[j] = (_Float16)0.f;
        }
        *(h8v*)(f1h + (size_t)m * 128 + c * 8) = v;
        return;
    }
    idx -= F_N;
    if (idx < A_N) {     // idx = k*512 + n, k<256
        int k = idx >> 9, n = idx & 511;
        float s = 0.f;
#pragma unroll 8
        for (int j = 0; j < 64; j++) s += fc0_w[k * 64 + j] * W0[j * 512 + n];
        Wc0t[n * 256 + k] = (_Float16)s;
        return;
    }
    idx -= A_N;
    if (idx < B_N) {     // idx = k*512 + n, k<128
        int k = idx >> 9, n = idx & 511;
        float s = 0.f;
#pragma unroll 8
        for (int j = 0; j < 64; j++) s += fc1_w[k * 64 + j] * W0[j * 512 + n];
        Wc1t[n * 128 + k] = (_Float16)s;
        return;
    }
    idx -= B_N;
    if (idx < C_N) {     // read 8 rows of W1 coalesced, 16B write
        int kc = idx >> 9, n = idx & 511;
        h8v v;
#pragma unroll
        for (int j = 0; j < 8; j++) v[j] = (_Float16)W1[(size_t)(kc * 8 + j) * 512 + n];
        *(h8v*)(W1t + (size_t)n * 512 + kc * 8) = v;
        return;
    }
    idx -= C_N;
    if (idx < D_N) {     // idx = t*512 + n
        int t = idx >> 9, n = idx & 511;
        const float* fb = t ? fc1_b : fc0_b;
        float s = 0.f;
#pragma unroll 8
        for (int j = 0; j < 64; j++) s += fb[j] * W0[j * 512 + n];
        biasF[t * 512 + n] = s;
        return;
    }
    idx -= D_N;
    if (idx < W2H_N) {   // W2hT[c][j0..j0+7] = f16(W2[j][c]), class-major
        int c = idx >> 6, j0 = (idx & 63) * 8;
        h8v v;
#pragma unroll
        for (int t = 0; t < 8; t++) v[t] = (_Float16)W2[(size_t)(j0 + t) * NCLS + c];
        *(h8v*)(W2hT + (size_t)c * 512 + j0) = v;
        return;
    }
    idx -= W2H_N;
    if (idx < N_EDGES) tick[idx] = atomicAdd(&cnt[dst[idx]], 1);
}

// ---------------------------------------------------------------------------
// CSR scan: parallel 3-kernel scan (proven)
// ---------------------------------------------------------------------------
#define NBLK_SCAN 196  // ceil(50000/256)

__global__ void scan_part(const int* __restrict__ cnt, int* __restrict__ part) {
    __shared__ int s[256];
    int i = blockIdx.x * 256 + threadIdx.x;
    s[threadIdx.x] = (i < N_NODES) ? cnt[i] : 0;
    __syncthreads();
    for (int off = 128; off; off >>= 1) {
        if (threadIdx.x < off) s[threadIdx.x] += s[threadIdx.x + off];
        __syncthreads();
    }
    if (threadIdx.x == 0) part[blockIdx.x] = s[0];
}

__global__ void scan_offs(int* __restrict__ part) {
    __shared__ int s[256];
    int tid = threadIdx.x;
    int v = (tid < NBLK_SCAN) ? part[tid] : 0;
    s[tid] = v;
    __syncthreads();
    for (int off = 1; off < 256; off <<= 1) {
        int x = (tid >= off) ? s[tid - off] : 0;
        __syncthreads();
        s[tid] += x;
        __syncthreads();
    }
    if (tid < NBLK_SCAN) part[tid] = s[tid] - v;  // exclusive
}

__global__ void scan_apply(const int* __restrict__ cnt, const int* __restrict__ part,
                           int* __restrict__ rp) {
    __shared__ int s[256];
    int tid = threadIdx.x;
    int i = blockIdx.x * 256 + tid;
    int v = (i < N_NODES) ? cnt[i] : 0;
    s[tid] = v;
    __syncthreads();
    for (int off = 1; off < 256; off <<= 1) {
        int x = (tid >= off) ? s[tid - off] : 0;
        __syncthreads();
        s[tid] += x;
        __syncthreads();
    }
    if (i < N_NODES) rp[i] = s[tid] - v + part[blockIdx.x];
    if (i == 0) rp[N_NODES] = N_EDGES;
}

// ---------------------------------------------------------------------------
// GEMM tile body (device fn): 128x256 tile, 8 waves, BK=32, XOR-4 swizzle.
// PROVEN structure (r9). BK=64 (r10) regressed -25% occupancy > barrier gain.
// ---------------------------------------------------------------------------
__device__ __forceinline__ void gemm_tile(
        const _Float16* __restrict__ A, const _Float16* __restrict__ Bt,
        _Float16* __restrict__ Cb, const float* __restrict__ al,
        const float* __restrict__ ar, const float* __restrict__ cbias,
        float* __restrict__ el, float* __restrict__ er,
        int M, int K, int row_off, int ytiles, int bid,
        _Float16* Asl, _Float16* Bsl) {
    int k8 = bid & 7, jj = bid >> 3;
    int y = k8 + 8 * (jj >> 1);
    if (y >= ytiles) return;
    int m0 = y * 128;
    int n0 = (jj & 1) * 256;
    int t = threadIdx.x;
    int lane = t & 63;
    int w = t >> 6;
    int wm = (w & 1) * 64, wn = (w >> 1) * 64;
    int l15 = lane & 15, quad = lane >> 4;
    f32x4 acc[4][4];
#pragma unroll
    for (int i = 0; i < 4; i++)
#pragma unroll
        for (int j = 0; j < 4; j++) acc[i][j] = (f32x4){0.f, 0.f, 0.f, 0.f};

    int fbA = t * 16;
    int rowA = fbA >> 6, kgA = ((fbA >> 4) & 3) ^ (rowA & 3);
    int fbB0 = t * 16;
    int fbB1 = fbB0 + 8192;
    int rowB0 = fbB0 >> 6, kgB0 = ((fbB0 >> 4) & 3) ^ (rowB0 & 3);
    int rowB1 = fbB1 >> 6, kgB1 = ((fbB1 >> 4) & 3) ^ (rowB1 & 3);

    for (int k0 = 0; k0 < K; k0 += 32) {
        GLD_LDS16(A + (size_t)(m0 + rowA) * K + k0 + kgA * 8, (char*)Asl + fbA);
        GLD_LDS16(Bt + (size_t)(n0 + rowB0) * K + k0 + kgB0 * 8, (char*)Bsl + fbB0);
        GLD_LDS16(Bt + (size_t)(n0 + rowB1) * K + k0 + kgB1 * 8, (char*)Bsl + fbB1);
        __syncthreads();
        f16x8 af[4], bfr[4];
#pragma unroll
        for (int i = 0; i < 4; i++) {
            int r = wm + i * 16 + l15;
            int kg = quad ^ (r & 3);
            af[i] = *(const f16x8*)(Asl + r * 32 + kg * 8);
        }
#pragma unroll
        for (int j = 0; j < 4; j++) {
            int r = wn + j * 16 + l15;
            int kg = quad ^ (r & 3);
            bfr[j] = *(const f16x8*)(Bsl + r * 32 + kg * 8);
        }
#pragma unroll
        for (int i = 0; i < 4; i++)
#pragma unroll
            for (int j = 0; j < 4; j++)
                acc[i][j] = __builtin_amdgcn_mfma_f32_16x16x32_f16(af[i], bfr[j], acc[i][j], 0, 0, 0);
        __syncthreads();
    }
    float cb[4];
#pragma unroll
    for (int j = 0; j < 4; j++)
        cb[j] = cbias ? cbias[n0 + wn + j * 16 + l15] : 0.f;
    // C/D layout: col = l15, row = quad*4 + reg  [m89/m91 verified]
#pragma unroll
    for (int i = 0; i < 4; i++) {
        int rbase = m0 + wm + i * 16 + quad * 4;
#pragma unroll
        for (int j = 0; j < 4; j++) {
            int col = n0 + wn + j * 16 + l15;
#pragma unroll
            for (int r = 0; r < 4; r++) {
                int row = rbase + r;
                if (row < M)
                    Cb[(size_t)(row_off + row) * HD + col] = (_Float16)(acc[i][j][r] + cb[j]);
            }
        }
    }
    int h = (n0 + wn) >> 6;
    float alv[4], arv[4];
#pragma unroll
    for (int j = 0; j < 4; j++) {
        alv[j] = al[h * 64 + j * 16 + l15];
        arv[j] = ar[h * 64 + j * 16 + l15];
    }
#pragma unroll
    for (int i = 0; i < 4; i++) {
#pragma unroll
        for (int r = 0; r < 4; r++) {
            float sl = 0.f, sr = 0.f;
#pragma unroll
            for (int j = 0; j < 4; j++) {
                float v = acc[i][j][r] + cb[j];
                sl += v * alv[j]; sr += v * arv[j];
            }
#pragma unroll
            for (int mk = 1; mk < 16; mk <<= 1) {
                sl += __shfl_xor(sl, mk);
                sr += __shfl_xor(sr, mk);
            }
            int row = m0 + wm + i * 16 + quad * 4 + r;
            if (l15 == 0 && row < M) {
                el[(size_t)(row_off + row) * HEADS + h] = sl;
                er[(size_t)(row_off + row) * HEADS + h] = sr;
            }
        }
    }
}

// ---------------------------------------------------------------------------
// Heterogeneous fused launch: scatter blocks + L0a GEMM blocks + L0b blocks.
// Scatter is atomic-free (ticket from prep).
// ---------------------------------------------------------------------------
#define SCAT_BLKS 128
#define G0A_BLKS (8 * 2 * ((235 + 7) / 8))  // 480
#define G0B_BLKS (8 * 2 * ((157 + 7) / 8))  // 320

__global__ __launch_bounds__(512) void scatter_gemm0(
        const int* __restrict__ src, const int* __restrict__ dst,
        const int* __restrict__ rp, const int* __restrict__ tick,
        int* __restrict__ srcs,
        const _Float16* __restrict__ f0h, const _Float16* __restrict__ Wc0t,
        const _Float16* __restrict__ f1h, const _Float16* __restrict__ Wc1t,
        _Float16* __restrict__ featA, const float* __restrict__ al0,
        const float* __restrict__ ar0, const float* __restrict__ biasF,
        float* __restrict__ el, float* __restrict__ er) {
    __shared__ _Float16 Asl[128 * 32];
    __shared__ _Float16 Bsl[256 * 32];
    int bid = blockIdx.x;
    if (bid < SCAT_BLKS) {
        for (int t = bid * 512 + threadIdx.x; t < N_EDGES; t += SCAT_BLKS * 512) {
            srcs[rp[dst[t]] + tick[t]] = src[t];
        }
        return;
    }
    bid -= SCAT_BLKS;
    if (bid < G0A_BLKS) {
        gemm_tile(f0h, Wc0t, featA, al0, ar0, biasF, el, er,
                  30000, 256, 0, 235, bid, Asl, Bsl);
        return;
    }
    bid -= G0A_BLKS;
    gemm_tile(f1h, Wc1t, featA, al0, ar0, biasF + 512, el, er,
              20000, 128, 30000, 157, bid, Asl, Bsl);
}

// ---------------------------------------------------------------------------
// Standalone wide GEMM (layer 1)
// ---------------------------------------------------------------------------
__global__ __launch_bounds__(512) void gemm_mfma_wide(const _Float16* __restrict__ A,
                                                      const _Float16* __restrict__ Bt,
                                                      _Float16* __restrict__ Cb,
                                                      const float* __restrict__ al,
                                                      const float* __restrict__ ar,
                                                      float* __restrict__ el,
                                                      float* __restrict__ er,
                                                      int M, int K, int ytiles) {
    __shared__ _Float16 Asl[128 * 32];
    __shared__ _Float16 Bsl[256 * 32];
    gemm_tile(A, Bt, Cb, al, ar, nullptr, el, er, M, K, 0, ytiles,
              blockIdx.x, Asl, Bsl);
}

// ---------------------------------------------------------------------------
// Fused edge softmax + aggregation, one wave per block (proven structure,
// ~88 us = random-gather memory-path floor per r2-r4 ablations).
// ---------------------------------------------------------------------------
__global__ __launch_bounds__(64) void attn_agg(
        const int* __restrict__ rp, const int* __restrict__ srcs,
        const float* __restrict__ el, const float* __restrict__ er,
        const _Float16* __restrict__ feat, const float* __restrict__ bias,
        _Float16* __restrict__ out) {
    __shared__ float aS[592];   // [0..575] alpha (p*9+h), [576..583] inv, [584..591] m
    __shared__ int   sS[64];
    int lane = threadIdx.x;
    int n    = blockIdx.x;
    int s0 = rp[n], s1 = rp[n + 1];
    int deg = s1 - s0;
    float er8[8];
    {
        f32x4 a = *(const f32x4*)(er + (size_t)n * 8);
        f32x4 b = *(const f32x4*)(er + (size_t)n * 8 + 4);
        er8[0]=a[0]; er8[1]=a[1]; er8[2]=a[2]; er8[3]=a[3];
        er8[4]=b[0]; er8[5]=b[1]; er8[6]=b[2]; er8[7]=b[3];
    }
    bool fast = (deg <= 64);
    if (fast) {
        bool act = lane < deg;
        int sp = act ? srcs[s0 + lane] : 0;
        sS[lane] = sp;
        f32x4 ea = {0.f,0.f,0.f,0.f}, eb = {0.f,0.f,0.f,0.f};
        if (act) {
            ea = *(const f32x4*)(el + (size_t)sp * 8);
            eb = *(const f32x4*)(el + (size_t)sp * 8 + 4);
        }
        float e8[8] = {ea[0],ea[1],ea[2],ea[3],eb[0],eb[1],eb[2],eb[3]};
#pragma unroll
        for (int h = 0; h < 8; h++) {
            float e = e8[h] + er8[h];
            e = e > 0.f ? e : 0.2f * e;
            e8[h] = act ? e : -1e30f;
        }
#pragma unroll
        for (int h = 0; h < 8; h++) {
            float mm = e8[h];
#pragma unroll
            for (int mk = 1; mk < 64; mk <<= 1) mm = fmaxf(mm, __shfl_xor(mm, mk));
            float pv = act ? __expf(e8[h] - mm) : 0.f;
            float ss = pv;
#pragma unroll
            for (int mk = 1; mk < 64; mk <<= 1) ss += __shfl_xor(ss, mk);
            aS[lane * 9 + h] = pv * (1.f / fmaxf(ss, 1e-9f));  // pre-scaled alpha
        }
    } else {
        float m8[8], s8[8];
#pragma unroll
        for (int h = 0; h < 8; h++) { m8[h] = -1e30f; s8[h] = 0.f; }
        for (int base = s0; base < s1; base += 64) {
            bool act = base + lane < s1;
            int sp = act ? srcs[base + lane] : 0;
            f32x4 ea = {0.f,0.f,0.f,0.f}, eb = {0.f,0.f,0.f,0.f};
            if (act) {
                ea = *(const f32x4*)(el + (size_t)sp * 8);
                eb = *(const f32x4*)(el + (size_t)sp * 8 + 4);
            }
            float ev[8] = {ea[0],ea[1],ea[2],ea[3],eb[0],eb[1],eb[2],eb[3]};
#pragma unroll
            for (int h = 0; h < 8; h++) {
                float e = ev[h] + er8[h];
                e = e > 0.f ? e : 0.2f * e;
                e = act ? e : -1e30f;
                float cm = e;
#pragma unroll
                for (int mk = 1; mk < 64; mk <<= 1) cm = fmaxf(cm, __shfl_xor(cm, mk));
                float nm = fmaxf(m8[h], cm);
                float pv = act ? __expf(e - nm) : 0.f;
#pragma unroll
                for (int mk = 1; mk < 64; mk <<= 1) pv += __shfl_xor(pv, mk);
                s8[h] = s8[h] * __expf(m8[h] - nm) + pv;
                m8[h] = nm;
            }
        }
        if (lane == 0) {
#pragma unroll
            for (int h = 0; h < 8; h++) {
                aS[576 + h] = 1.f / fmaxf(s8[h], 1e-9f);
                aS[584 + h] = m8[h];
            }
        }
    }
    // wave-private LDS handoff (lockstep wave + compiler lgkmcnt ordering)
    __builtin_amdgcn_wave_barrier();
    int hh = lane >> 3, d0 = (lane & 7) * 8;   // lane*8 = hh*64 + d0
    h8v z = {(_Float16)0, (_Float16)0, (_Float16)0, (_Float16)0,
             (_Float16)0, (_Float16)0, (_Float16)0, (_Float16)0};
    h8v acc0 = z, acc1 = z, acc2 = z, acc3 = z;
    const _Float16* colbase = feat + hh * 64 + d0;
    if (fast) {
        int p = 0;
        for (; p + 4 <= deg; p += 4) {
            int spa = sS[p],     spb = sS[p + 1];
            int spc = sS[p + 2], spd = sS[p + 3];
            _Float16 aa = (_Float16)aS[p * 9 + hh];
            _Float16 ab = (_Float16)aS[(p + 1) * 9 + hh];
            _Float16 ac = (_Float16)aS[(p + 2) * 9 + hh];
            _Float16 ad = (_Float16)aS[(p + 3) * 9 + hh];
            h8v fa = *(const h8v*)(colbase + (size_t)spa * HD);
            h8v fb = *(const h8v*)(colbase + (size_t)spb * HD);
            h8v fc = *(const h8v*)(colbase + (size_t)spc * HD);
            h8v fd = *(const h8v*)(colbase + (size_t)spd * HD);
            h8v a8a = {aa, aa, aa, aa, aa, aa, aa, aa};
            h8v a8b = {ab, ab, ab, ab, ab, ab, ab, ab};
            h8v a8c = {ac, ac, ac, ac, ac, ac, ac, ac};
            h8v a8d = {ad, ad, ad, ad, ad, ad, ad, ad};
            acc0 += a8a * fa;
            acc1 += a8b * fb;
            acc2 += a8c * fc;
            acc3 += a8d * fd;
        }
        for (; p < deg; p++) {
            int sp = sS[p];
            _Float16 ah = (_Float16)aS[p * 9 + hh];
            h8v a8 = {ah, ah, ah, ah, ah, ah, ah, ah};
            h8v f = *(const h8v*)(colbase + (size_t)sp * HD);
            acc0 += a8 * f;
        }
    } else {
        float inv_l = aS[576 + hh];
        float m_l   = aS[584 + hh];
        float ern_l = er[(size_t)n * 8 + hh];
        for (int p = s0; p < s1; p++) {
            int sp = srcs[p];
            float e = el[(size_t)sp * 8 + hh] + ern_l;
            e = e > 0.f ? e : 0.2f * e;
            _Float16 ah = (_Float16)(__expf(e - m_l) * inv_l);
            h8v a8 = {ah, ah, ah, ah, ah, ah, ah, ah};
            h8v f = *(const h8v*)(colbase + (size_t)sp * HD);
            acc0 += a8 * f;
        }
    }
    acc0 += acc1; acc2 += acc3; acc0 += acc2;
    float4 b0v = *(const float4*)(bias + lane * 8);
    float4 b1v = *(const float4*)(bias + lane * 8 + 4);
    float bb[8] = {b0v.x,b0v.y,b0v.z,b0v.w,b1v.x,b1v.y,b1v.z,b1v.w};
    h8v o;
#pragma unroll
    for (int j = 0; j < 8; j++) {
        float x = (float)acc0[j] + bb[j];
        x = x > 0.f ? x : __expf(x) - 1.f;
        o[j] = (_Float16)x;
    }
    *(h8v*)(out + (size_t)n * HD + lane * 8) = o;
}

// ---------------------------------------------------------------------------
// Layer-2 variant: softmax+aggregation + fused [512->10] W2 projection.
// W2hT (10KB, L2-resident) is PRELOADED into registers at kernel entry —
// its load latency hides entirely under the softmax+gather phases instead of
// serializing at the epilogue. +20 VGPR (32->52), no occupancy impact at
// 1-wave blocks.
// ---------------------------------------------------------------------------
__global__ __launch_bounds__(64) void attn_agg_l2(
        const int* __restrict__ rp, const int* __restrict__ srcs,
        const float* __restrict__ el, const float* __restrict__ er,
        const _Float16* __restrict__ feat, const float* __restrict__ bias,
        const _Float16* __restrict__ W2hT, const float* __restrict__ al2,
        const float* __restrict__ ar2, float* __restrict__ feat2,
        float* __restrict__ el2, float* __restrict__ er2) {
    __shared__ float aS[592];
    __shared__ int   sS[64];
    int lane = threadIdx.x;
    int n    = blockIdx.x;
    int s0 = rp[n], s1 = rp[n + 1];
    int deg = s1 - s0;
    // early-issue W2 loads (independent of everything; L2-resident)
    h8v w2v[10];
    {
        const _Float16* w2base = W2hT + lane * 8;
#pragma unroll
        for (int c = 0; c < NCLS; c++) w2v[c] = *(const h8v*)(w2base + (size_t)c * 512);
    }
    float er8[8];
    {
        f32x4 a = *(const f32x4*)(er + (size_t)n * 8);
        f32x4 b = *(const f32x4*)(er + (size_t)n * 8 + 4);
        er8[0]=a[0]; er8[1]=a[1]; er8[2]=a[2]; er8[3]=a[3];
        er8[4]=b[0]; er8[5]=b[1]; er8[6]=b[2]; er8[7]=b[3];
    }
    bool fast = (deg <= 64);
    if (fast) {
        bool act = lane < deg;
        int sp = act ? srcs[s0 + lane] : 0;
        sS[lane] = sp;
        f32x4 ea = {0.f,0.f,0.f,0.f}, eb = {0.f,0.f,0.f,0.f};
        if (act) {
            ea = *(const f32x4*)(el + (size_t)sp * 8);
            eb = *(const f32x4*)(el + (size_t)sp * 8 + 4);
        }
        float e8[8] = {ea[0],ea[1],ea[2],ea[3],eb[0],eb[1],eb[2],eb[3]};
#pragma unroll
        for (int h = 0; h < 8; h++) {
            float e = e8[h] + er8[h];
            e = e > 0.f ? e : 0.2f * e;
            e8[h] = act ? e : -1e30f;
        }
#pragma unroll
        for (int h = 0; h < 8; h++) {
            float mm = e8[h];
#pragma unroll
            for (int mk = 1; mk < 64; mk <<= 1) mm = fmaxf(mm, __shfl_xor(mm, mk));
            float pv = act ? __expf(e8[h] - mm) : 0.f;
            float ss = pv;
#pragma unroll
            for (int mk = 1; mk < 64; mk <<= 1) ss += __shfl_xor(ss, mk);
            aS[lane * 9 + h] = pv * (1.f / fmaxf(ss, 1e-9f));
        }
    } else {
        float m8[8], s8[8];
#pragma unroll
        for (int h = 0; h < 8; h++) { m8[h] = -1e30f; s8[h] = 0.f; }
        for (int base = s0; base < s1; base += 64) {
            bool act = base + lane < s1;
            int sp = act ? srcs[base + lane] : 0;
            f32x4 ea = {0.f,0.f,0.f,0.f}, eb = {0.f,0.f,0.f,0.f};
            if (act) {
                ea = *(const f32x4*)(el + (size_t)sp * 8);
                eb = *(const f32x4*)(el + (size_t)sp * 8 + 4);
            }
            float ev[8] = {ea[0],ea[1],ea[2],ea[3],eb[0],eb[1],eb[2],eb[3]};
#pragma unroll
            for (int h = 0; h < 8; h++) {
                float e = ev[h] + er8[h];
                e = e > 0.f ? e : 0.2f * e;
                e = act ? e : -1e30f;
                float cm = e;
#pragma unroll
                for (int mk = 1; mk < 64; mk <<= 1) cm = fmaxf(cm, __shfl_xor(cm, mk));
                float nm = fmaxf(m8[h], cm);
                float pv = act ? __expf(e - nm) : 0.f;
#pragma unroll
                for (int mk = 1; mk < 64; mk <<= 1) pv += __shfl_xor(pv, mk);
                s8[h] = s8[h] * __expf(m8[h] - nm) + pv;
                m8[h] = nm;
            }
        }
        if (lane == 0) {
#pragma unroll
            for (int h = 0; h < 8; h++) {
                aS[576 + h] = 1.f / fmaxf(s8[h], 1e-9f);
                aS[584 + h] = m8[h];
            }
        }
    }
    __builtin_amdgcn_wave_barrier();
    int hh = lane >> 3, d0 = (lane & 7) * 8;
    h8v z = {(_Float16)0, (_Float16)0, (_Float16)0, (_Float16)0,
             (_Float16)0, (_Float16)0, (_Float16)0, (_Float16)0};
    h8v acc0 = z, acc1 = z, acc2 = z, acc3 = z;
    const _Float16* colbase = feat + hh * 64 + d0;
    if (fast) {
        int p = 0;
        for (; p + 4 <= deg; p += 4) {
            int spa = sS[p],     spb = sS[p + 1];
            int spc = sS[p + 2], spd = sS[p + 3];
            _Float16 aa = (_Float16)aS[p * 9 + hh];
            _Float16 ab = (_Float16)aS[(p + 1) * 9 + hh];
            _Float16 ac = (_Float16)aS[(p + 2) * 9 + hh];
            _Float16 ad = (_Float16)aS[(p + 3) * 9 + hh];
            h8v fa = *(const h8v*)(colbase + (size_t)spa * HD);
            h8v fb = *(const h8v*)(colbase + (size_t)spb * HD);
            h8v fc = *(const h8v*)(colbase + (size_t)spc * HD);
            h8v fd = *(const h8v*)(colbase + (size_t)spd * HD);
            h8v a8a = {aa, aa, aa, aa, aa, aa, aa, aa};
            h8v a8b = {ab, ab, ab, ab, ab, ab, ab, ab};
            h8v a8c = {ac, ac, ac, ac, ac, ac, ac, ac};
            h8v a8d = {ad, ad, ad, ad, ad, ad, ad, ad};
            acc0 += a8a * fa;
            acc1 += a8b * fb;
            acc2 += a8c * fc;
            acc3 += a8d * fd;
        }
        for (; p < deg; p++) {
            int sp = sS[p];
            _Float16 ah = (_Float16)aS[p * 9 + hh];
            h8v a8 = {ah, ah, ah, ah, ah, ah, ah, ah};
            h8v f = *(const h8v*)(colbase + (size_t)sp * HD);
            acc0 += a8 * f;
        }
    } else {
        float inv_l = aS[576 + hh];
        float m_l   = aS[584 + hh];
        float ern_l = er[(size_t)n * 8 + hh];
        for (int p = s0; p < s1; p++) {
            int sp = srcs[p];
            float e = el[(size_t)sp * 8 + hh] + ern_l;
            e = e > 0.f ? e : 0.2f * e;
            _Float16 ah = (_Float16)(__expf(e - m_l) * inv_l);
            h8v a8 = {ah, ah, ah, ah, ah, ah, ah, ah};
            h8v f = *(const h8v*)(colbase + (size_t)sp * HD);
            acc0 += a8 * f;
        }
    }
    acc0 += acc1; acc2 += acc3; acc0 += acc2;
    float4 b0v = *(const float4*)(bias + lane * 8);
    float4 b1v = *(const float4*)(bias + lane * 8 + 4);
    float bb[8] = {b0v.x,b0v.y,b0v.z,b0v.w,b1v.x,b1v.y,b1v.z,b1v.w};
    float x[8];
#pragma unroll
    for (int j = 0; j < 8; j++) {
        float v = (float)acc0[j] + bb[j];
        x[j] = v > 0.f ? v : __expf(v) - 1.f;     // ELU in f32 (layer-1 act)
    }
    // fused [512->10] projection: lane owns j-cols lane*8..lane*8+7.
    float s[NCLS];
#if __has_builtin(__builtin_amdgcn_fdot2)
    h2v xh[4];
#pragma unroll
    for (int j = 0; j < 4; j++)
        xh[j] = (h2v){(_Float16)x[2 * j], (_Float16)x[2 * j + 1]};
#pragma unroll
    for (int c = 0; c < NCLS; c++) {
        h8v w = w2v[c];
        float acc = 0.f;
#pragma unroll
        for (int jp = 0; jp < 4; jp++) {
            h2v wp = (h2v){w[2 * jp], w[2 * jp + 1]};
            acc = __builtin_amdgcn_fdot2(xh[jp], wp, acc, false);
        }
        s[c] = acc;
    }
#else
#pragma unroll
    for (int c = 0; c < NCLS; c++) {
        h8v w = w2v[c];
        float acc = 0.f;
#pragma unroll
        for (int j = 0; j < 8; j++) acc += x[j] * (float)w[j];
        s[c] = acc;
    }
#endif
#pragma unroll
    for (int c = 0; c < NCLS; c++)
#pragma unroll
        for (int mk = 1; mk < 64; mk <<= 1) s[c] += __shfl_xor(s[c], mk);
    if (lane == 0) {
        float e1 = 0.f, e2 = 0.f;
#pragma unroll
        for (int c = 0; c < NCLS; c++) { e1 += s[c] * al2[c]; e2 += s[c] * ar2[c]; }
        el2[n] = e1; er2[n] = e2;
#pragma unroll
        for (int c = 0; c < NCLS; c++) feat2[(size_t)n * F2S + c] = s[c];
    }
}

// ---------------------------------------------------------------------------
// layer 2 fused softmax+aggregation (H=1, D=10), one wave per block.
// feat2 rows padded to stride 12 -> 3x f32x4 vector loads.
// ---------------------------------------------------------------------------
__global__ __launch_bounds__(64) void attn2_agg2(
        const int* __restrict__ rp, const int* __restrict__ srcs,
        const float* __restrict__ el, const float* __restrict__ er,
        const float* __restrict__ feat2, const float* __restrict__ b2,
        float* __restrict__ out) {
    int lane = threadIdx.x;
    int n = blockIdx.x;
    int s0 = rp[n], s1 = rp[n + 1], deg = s1 - s0;
    float ern = er[n];
    float facc[NCLS];
#pragma unroll
    for (int c = 0; c < NCLS; c++) facc[c] = 0.f;
    if (deg <= 64) {
        bool act = lane < deg;
        int sp = act ? srcs[s0 + lane] : 0;
        float e = act ? el[sp] + ern : 0.f;
        e = e > 0.f ? e : 0.2f * e;
        if (!act) e = -1e30f;
        float mm = e;
#pragma unroll
        for (int mk = 1; mk < 64; mk <<= 1) mm = fmaxf(mm, __shfl_xor(mm, mk));
        float pv = act ? __expf(e - mm) : 0.f;
        float ss = pv;
#pragma unroll
        for (int mk = 1; mk < 64; mk <<= 1) ss += __shfl_xor(ss, mk);
        float a = pv / fmaxf(ss, 1e-9f);
        if (act) {
            const float* fr = feat2 + (size_t)sp * F2S;
            f32x4 fa = *(const f32x4*)fr;
            f32x4 fb = *(const f32x4*)(fr + 4);
            f32x4 fc = *(const f32x4*)(fr + 8);
            float fv[NCLS] = {fa[0],fa[1],fa[2],fa[3],fb[0],fb[1],fb[2],fb[3],fc[0],fc[1]};
#pragma unroll
            for (int c = 0; c < NCLS; c++) facc[c] = a * fv[c];
        }
    } else {
        float mm = -1e30f, ssum = 0.f;
        for (int base = s0; base < s1; base += 64) {
            bool act = base + lane < s1;
            int sp = act ? srcs[base + lane] : 0;
            float e = act ? el[sp] + ern : 0.f;
            e = e > 0.f ? e : 0.2f * e;
            if (!act) e = -1e30f;
            float cm = e;
#pragma unroll
            for (int mk = 1; mk < 64; mk <<= 1) cm = fmaxf(cm, __shfl_xor(cm, mk));
            float nm = fmaxf(mm, cm);
            float pv = act ? __expf(e - nm) : 0.f;
#pragma unroll
            for (int mk = 1; mk < 64; mk <<= 1) pv += __shfl_xor(pv, mk);
            ssum = ssum * __expf(mm - nm) + pv;
            mm = nm;
        }
        float inv = 1.f / fmaxf(ssum, 1e-9f);
        for (int base = s0; base < s1; base += 64) {
            bool act = base + lane < s1;
            int sp = act ? srcs[base + lane] : 0;
            float e = act ? el[sp] + ern : 0.f;
            e = e > 0.f ? e : 0.2f * e;
            float a = act ? __expf(e - mm) * inv : 0.f;
            if (act) {
                const float* fr = feat2 + (size_t)sp * F2S;
                f32x4 fa = *(const f32x4*)fr;
                f32x4 fb = *(const f32x4*)(fr + 4);
                f32x4 fc = *(const f32x4*)(fr + 8);
                float fv[NCLS] = {fa[0],fa[1],fa[2],fa[3],fb[0],fb[1],fb[2],fb[3],fc[0],fc[1]};
#pragma unroll
                for (int c = 0; c < NCLS; c++) facc[c] += a * fv[c];
            }
        }
    }
#pragma unroll
    for (int c = 0; c < NCLS; c++)
#pragma unroll
        for (int mk = 1; mk < 64; mk <<= 1) facc[c] += __shfl_xor(facc[c], mk);
    if (lane == 0) {
#pragma unroll
        for (int c = 0; c < NCLS; c++) out[(size_t)n * NCLS + c] = facc[c] + b2[c];
    }
}

// ---------------------------------------------------------------------------
extern "C" void kernel_launch(void* const* d_in, const int* in_sizes, int n_in,
                              void* d_out, int out_size, void* d_ws, size_t ws_size,
                              hipStream_t stream) {
    const float* feat0 = (const float*)d_in[0];
    const float* feat1 = (const float*)d_in[1];
    const float* fc0_w = (const float*)d_in[2];
    const float* fc0_b = (const float*)d_in[3];
    const float* fc1_w = (const float*)d_in[4];
    const float* fc1_b = (const float*)d_in[5];
    const float* W0    = (const float*)d_in[6];
    const float* al0   = (const float*)d_in[7];
    const float* ar0   = (const float*)d_in[8];
    const float* b0    = (const float*)d_in[9];
    const float* W1    = (const float*)d_in[10];
    const float* al1   = (const float*)d_in[11];
    const float* ar1   = (const float*)d_in[12];
    const float* b1    = (const float*)d_in[13];
    const float* W2    = (const float*)d_in[14];
    const float* al2   = (const float*)d_in[15];
    const float* ar2   = (const float*)d_in[16];
    const float* b2    = (const float*)d_in[17];
    const int* eidx    = (const int*)d_in[18];
    const int* src = eidx;
    const int* dst = eidx + N_EDGES;
    float* out = (float*)d_out;

    char* ws = (char*)d_ws;
    size_t off = 0;
    auto alloc = [&](size_t bytes) { size_t o = off; off = (off + bytes + 255) & ~(size_t)255; return o; };

    _Float16* featA = (_Float16*)(ws + alloc((size_t)M_PAD * HD * 2));
    _Float16* aggh  = (_Float16*)(ws + alloc((size_t)M_PAD * HD * 2));
    _Float16* f0h   = (_Float16*)(ws + alloc((size_t)F0ROWS * 256 * 2));
    _Float16* f1h   = (_Float16*)(ws + alloc((size_t)F1ROWS * 128 * 2));
    float*    feat2 = (float*)(ws + alloc((size_t)N_NODES * F2S * 4));
    float*    el    = (float*)(ws + alloc((size_t)N_NODES * HEADS * 4));
    float*    er    = (float*)(ws + alloc((size_t)N_NODES * HEADS * 4));
    float*    el2   = (float*)(ws + alloc((size_t)N_NODES * 4));
    float*    er2   = (float*)(ws + alloc((size_t)N_NODES * 4));
    float*    biasF = (float*)(ws + alloc(1024 * 4));
    int*      cnt   = (int*)  (ws + alloc((size_t)N_NODES * 4));
    int*      rp    = (int*)  (ws + alloc((size_t)(N_NODES + 1) * 4));
    int*      tick  = (int*)  (ws + alloc((size_t)N_EDGES * 4));
    int*      srcs  = (int*)  (ws + alloc((size_t)N_EDGES * 4));
    int*      part  = (int*)  (ws + alloc(1024));
    _Float16* Wc0t  = (_Float16*)(ws + alloc(512 * 256 * 2));
    _Float16* Wc1t  = (_Float16*)(ws + alloc(512 * 128 * 2));
    _Float16* W1t   = (_Float16*)(ws + alloc(512 * 512 * 2));
    _Float16* W2hT  = (_Float16*)(ws + alloc(5120 * 2));

    // --- cnt zero, then prep (weight folds + casts + count/ticket fused) ---
    hipMemsetAsync(cnt, 0, N_NODES * sizeof(int), stream);
    prep<<<(PREP_TOTAL + 255) / 256, 256, 0, stream>>>(
        feat0, feat1, fc0_w, fc0_b, fc1_w, fc1_b, W0, W1, W2, dst,
        f0h, f1h, Wc0t, Wc1t, W1t, W2hT, biasF, cnt, tick);

    // --- CSR scan ---
    scan_part<<<NBLK_SCAN, 256, 0, stream>>>(cnt, part);
    scan_offs<<<1, 256, 0, stream>>>(part);
    scan_apply<<<NBLK_SCAN, 256, 0, stream>>>(cnt, part, rp);

    // --- fused: atomic-free scatter + layer-0 GEMMs (one launch) ---
    scatter_gemm0<<<SCAT_BLKS + G0A_BLKS + G0B_BLKS, 512, 0, stream>>>(
        src, dst, rp, tick, srcs, f0h, Wc0t, f1h, Wc1t, featA, al0, ar0, biasF, el, er);

    attn_agg<<<N_NODES, 64, 0, stream>>>(rp, srcs, el, er, featA, b0, aggh);

    // --- layer 1 ---
    int g1 = 8 * 2 * ((YTILES_L1 + 7) / 8);  // 784
    gemm_mfma_wide<<<g1, 512, 0, stream>>>(aggh, W1t, featA, al1, ar1, el, er,
                                           N_NODES, HD, YTILES_L1);

    // --- layer 1 attn + fused layer-2 projection ---
    attn_agg_l2<<<N_NODES, 64, 0, stream>>>(rp, srcs, el, er, featA, b1,
                                            W2hT, al2, ar2, feat2, el2, er2);

    // --- layer 2 softmax+agg ---
    attn2_agg2<<<N_NODES, 64, 0, stream>>>(rp, srcs, el2, er2, feat2, b2, out);
}

// Round 12
// 442.760 us; speedup vs baseline: 1.0458x; 1.0261x over previous
//
#include <hip/hip_runtime.h>
#include <hip/hip_bf16.h>
#include <hip/hip_fp16.h>

#define N_NODES 50000
#define N_EDGES 500000
#define HEADS 8
#define HID 64
#define HD 512   // HEADS*HID
#define NCLS 10
#define F2S 12   // feat2 row stride (floats), padded 10->12 for f32x4 loads
#define M_PAD 50048  // 391*128
#define YTILES_L1 391
#define F0ROWS 30080  // 235*128
#define F1ROWS 20096  // 157*128

typedef _Float16 f16x8 __attribute__((ext_vector_type(8)));
typedef _Float16 h8v   __attribute__((ext_vector_type(8)));
typedef _Float16 h2v   __attribute__((ext_vector_type(2)));
typedef float    f32x4 __attribute__((ext_vector_type(4)));

#define GLD_LDS16(g, l) __builtin_amdgcn_global_load_lds( \
    (__attribute__((address_space(1))) void*)(g),         \
    (__attribute__((address_space(3))) void*)(l), 16, 0, 0)

// ---------------------------------------------------------------------------
// prep: one launch, grid-strided sections, VECTORIZED (G13).
// Count section records the edge's ticket (atomicAdd return) for the
// atomic-free scatter.
// ---------------------------------------------------------------------------
#define E_N (F0ROWS * 32)    // 8 elems per thread, 256 cols -> 32 chunks
#define F_N (F1ROWS * 16)    // 128 cols -> 16 chunks
#define A_N (512 * 256)
#define B_N (512 * 128)
#define C_N (512 * 64)       // 64 k-chunks of 8, n inner (coalesced reads)
#define D_N 1024
#define W2H_N 640            // W2 [512][10] -> W2hT [10][512] f16, 8 j's/thread
#define PREP_TOTAL (E_N + F_N + A_N + B_N + C_N + D_N + W2H_N + N_EDGES)

__global__ void prep(const float* __restrict__ feat0, const float* __restrict__ feat1,
                     const float* __restrict__ fc0_w, const float* __restrict__ fc0_b,
                     const float* __restrict__ fc1_w, const float* __restrict__ fc1_b,
                     const float* __restrict__ W0, const float* __restrict__ W1,
                     const float* __restrict__ W2, const int* __restrict__ dst,
                     _Float16* __restrict__ f0h, _Float16* __restrict__ f1h,
                     _Float16* __restrict__ Wc0t, _Float16* __restrict__ Wc1t,
                     _Float16* __restrict__ W1t, _Float16* __restrict__ W2hT,
                     float* __restrict__ biasF, int* __restrict__ cnt,
                     int* __restrict__ tick) {
    int idx = blockIdx.x * 256 + threadIdx.x;
    if (idx < E_N) {
        int m = idx >> 5, c = idx & 31;
        h8v v;
        if (m < 30000) {
            f32x4 a = *(const f32x4*)(feat0 + (size_t)m * 256 + c * 8);
            f32x4 b = *(const f32x4*)(feat0 + (size_t)m * 256 + c * 8 + 4);
#pragma unroll
            for (int j = 0; j < 4; j++) { v[j] = (_Float16)a[j]; v[j+4] = (_Float16)b[j]; }
        } else {
#pragma unroll
            for (int j = 0; j < 8; j++) v[j] = (_Float16)0.f;
        }
        *(h8v*)(f0h + (size_t)m * 256 + c * 8) = v;
        return;
    }
    idx -= E_N;
    if (idx < F_N) {
        int m = idx >> 4, c = idx & 15;
        h8v v;
        if (m < 20000) {
            f32x4 a = *(const f32x4*)(feat1 + (size_t)m * 128 + c * 8);
            f32x4 b = *(const f32x4*)(feat1 + (size_t)m * 128 + c * 8 + 4);
#pragma unroll
            for (int j = 0; j < 4; j++) { v[j] = (_Float16)a[j]; v[j+4] = (_Float16)b[j]; }
        } else {
#pragma unroll
            for (int j = 0; j < 8; j++) v[j] = (_Float16)0.f;
        }
        *(h8v*)(f1h + (size_t)m * 128 + c * 8) = v;
        return;
    }
    idx -= F_N;
    if (idx < A_N) {     // idx = k*512 + n, k<256
        int k = idx >> 9, n = idx & 511;
        float s = 0.f;
#pragma unroll 8
        for (int j = 0; j < 64; j++) s += fc0_w[k * 64 + j] * W0[j * 512 + n];
        Wc0t[n * 256 + k] = (_Float16)s;
        return;
    }
    idx -= A_N;
    if (idx < B_N) {     // idx = k*512 + n, k<128
        int k = idx >> 9, n = idx & 511;
        float s = 0.f;
#pragma unroll 8
        for (int j = 0; j < 64; j++) s += fc1_w[k * 64 + j] * W0[j * 512 + n];
        Wc1t[n * 128 + k] = (_Float16)s;
        return;
    }
    idx -= B_N;
    if (idx < C_N) {     // read 8 rows of W1 coalesced, 16B write
        int kc = idx >> 9, n = idx & 511;
        h8v v;
#pragma unroll
        for (int j = 0; j < 8; j++) v[j] = (_Float16)W1[(size_t)(kc * 8 + j) * 512 + n];
        *(h8v*)(W1t + (size_t)n * 512 + kc * 8) = v;
        return;
    }
    idx -= C_N;
    if (idx < D_N) {     // idx = t*512 + n
        int t = idx >> 9, n = idx & 511;
        const float* fb = t ? fc1_b : fc0_b;
        float s = 0.f;
#pragma unroll 8
        for (int j = 0; j < 64; j++) s += fb[j] * W0[j * 512 + n];
        biasF[t * 512 + n] = s;
        return;
    }
    idx -= D_N;
    if (idx < W2H_N) {   // W2hT[c][j0..j0+7] = f16(W2[j][c]), class-major
        int c = idx >> 6, j0 = (idx & 63) * 8;
        h8v v;
#pragma unroll
        for (int t = 0; t < 8; t++) v[t] = (_Float16)W2[(size_t)(j0 + t) * NCLS + c];
        *(h8v*)(W2hT + (size_t)c * 512 + j0) = v;
        return;
    }
    idx -= W2H_N;
    if (idx < N_EDGES) tick[idx] = atomicAdd(&cnt[dst[idx]], 1);
}

// ---------------------------------------------------------------------------
// CSR scan: parallel 3-kernel scan (proven)
// ---------------------------------------------------------------------------
#define NBLK_SCAN 196  // ceil(50000/256)

__global__ void scan_part(const int* __restrict__ cnt, int* __restrict__ part) {
    __shared__ int s[256];
    int i = blockIdx.x * 256 + threadIdx.x;
    s[threadIdx.x] = (i < N_NODES) ? cnt[i] : 0;
    __syncthreads();
    for (int off = 128; off; off >>= 1) {
        if (threadIdx.x < off) s[threadIdx.x] += s[threadIdx.x + off];
        __syncthreads();
    }
    if (threadIdx.x == 0) part[blockIdx.x] = s[0];
}

__global__ void scan_offs(int* __restrict__ part) {
    __shared__ int s[256];
    int tid = threadIdx.x;
    int v = (tid < NBLK_SCAN) ? part[tid] : 0;
    s[tid] = v;
    __syncthreads();
    for (int off = 1; off < 256; off <<= 1) {
        int x = (tid >= off) ? s[tid - off] : 0;
        __syncthreads();
        s[tid] += x;
        __syncthreads();
    }
    if (tid < NBLK_SCAN) part[tid] = s[tid] - v;  // exclusive
}

__global__ void scan_apply(const int* __restrict__ cnt, const int* __restrict__ part,
                           int* __restrict__ rp) {
    __shared__ int s[256];
    int tid = threadIdx.x;
    int i = blockIdx.x * 256 + tid;
    int v = (i < N_NODES) ? cnt[i] : 0;
    s[tid] = v;
    __syncthreads();
    for (int off = 1; off < 256; off <<= 1) {
        int x = (tid >= off) ? s[tid - off] : 0;
        __syncthreads();
        s[tid] += x;
        __syncthreads();
    }
    if (i < N_NODES) rp[i] = s[tid] - v + part[blockIdx.x];
    if (i == 0) rp[N_NODES] = N_EDGES;
}

// ---------------------------------------------------------------------------
// GEMM tile body (device fn): 128x256 tile, 8 waves, BK=32, XOR-4 swizzle.
// PROVEN structure (r9). BK=64 (r10) regressed -25% occupancy > barrier gain.
// ---------------------------------------------------------------------------
__device__ __forceinline__ void gemm_tile(
        const _Float16* __restrict__ A, const _Float16* __restrict__ Bt,
        _Float16* __restrict__ Cb, const float* __restrict__ al,
        const float* __restrict__ ar, const float* __restrict__ cbias,
        float* __restrict__ el, float* __restrict__ er,
        int M, int K, int row_off, int ytiles, int bid,
        _Float16* Asl, _Float16* Bsl) {
    int k8 = bid & 7, jj = bid >> 3;
    int y = k8 + 8 * (jj >> 1);
    if (y >= ytiles) return;
    int m0 = y * 128;
    int n0 = (jj & 1) * 256;
    int t = threadIdx.x;
    int lane = t & 63;
    int w = t >> 6;
    int wm = (w & 1) * 64, wn = (w >> 1) * 64;
    int l15 = lane & 15, quad = lane >> 4;
    f32x4 acc[4][4];
#pragma unroll
    for (int i = 0; i < 4; i++)
#pragma unroll
        for (int j = 0; j < 4; j++) acc[i][j] = (f32x4){0.f, 0.f, 0.f, 0.f};

    int fbA = t * 16;
    int rowA = fbA >> 6, kgA = ((fbA >> 4) & 3) ^ (rowA & 3);
    int fbB0 = t * 16;
    int fbB1 = fbB0 + 8192;
    int rowB0 = fbB0 >> 6, kgB0 = ((fbB0 >> 4) & 3) ^ (rowB0 & 3);
    int rowB1 = fbB1 >> 6, kgB1 = ((fbB1 >> 4) & 3) ^ (rowB1 & 3);

    for (int k0 = 0; k0 < K; k0 += 32) {
        GLD_LDS16(A + (size_t)(m0 + rowA) * K + k0 + kgA * 8, (char*)Asl + fbA);
        GLD_LDS16(Bt + (size_t)(n0 + rowB0) * K + k0 + kgB0 * 8, (char*)Bsl + fbB0);
        GLD_LDS16(Bt + (size_t)(n0 + rowB1) * K + k0 + kgB1 * 8, (char*)Bsl + fbB1);
        __syncthreads();
        f16x8 af[4], bfr[4];
#pragma unroll
        for (int i = 0; i < 4; i++) {
            int r = wm + i * 16 + l15;
            int kg = quad ^ (r & 3);
            af[i] = *(const f16x8*)(Asl + r * 32 + kg * 8);
        }
#pragma unroll
        for (int j = 0; j < 4; j++) {
            int r = wn + j * 16 + l15;
            int kg = quad ^ (r & 3);
            bfr[j] = *(const f16x8*)(Bsl + r * 32 + kg * 8);
        }
#pragma unroll
        for (int i = 0; i < 4; i++)
#pragma unroll
            for (int j = 0; j < 4; j++)
                acc[i][j] = __builtin_amdgcn_mfma_f32_16x16x32_f16(af[i], bfr[j], acc[i][j], 0, 0, 0);
        __syncthreads();
    }
    float cb[4];
#pragma unroll
    for (int j = 0; j < 4; j++)
        cb[j] = cbias ? cbias[n0 + wn + j * 16 + l15] : 0.f;
    // C/D layout: col = l15, row = quad*4 + reg  [m89/m91 verified]
#pragma unroll
    for (int i = 0; i < 4; i++) {
        int rbase = m0 + wm + i * 16 + quad * 4;
#pragma unroll
        for (int j = 0; j < 4; j++) {
            int col = n0 + wn + j * 16 + l15;
#pragma unroll
            for (int r = 0; r < 4; r++) {
                int row = rbase + r;
                if (row < M)
                    Cb[(size_t)(row_off + row) * HD + col] = (_Float16)(acc[i][j][r] + cb[j]);
            }
        }
    }
    int h = (n0 + wn) >> 6;
    float alv[4], arv[4];
#pragma unroll
    for (int j = 0; j < 4; j++) {
        alv[j] = al[h * 64 + j * 16 + l15];
        arv[j] = ar[h * 64 + j * 16 + l15];
    }
#pragma unroll
    for (int i = 0; i < 4; i++) {
#pragma unroll
        for (int r = 0; r < 4; r++) {
            float sl = 0.f, sr = 0.f;
#pragma unroll
            for (int j = 0; j < 4; j++) {
                float v = acc[i][j][r] + cb[j];
                sl += v * alv[j]; sr += v * arv[j];
            }
#pragma unroll
            for (int mk = 1; mk < 16; mk <<= 1) {
                sl += __shfl_xor(sl, mk);
                sr += __shfl_xor(sr, mk);
            }
            int row = m0 + wm + i * 16 + quad * 4 + r;
            if (l15 == 0 && row < M) {
                el[(size_t)(row_off + row) * HEADS + h] = sl;
                er[(size_t)(row_off + row) * HEADS + h] = sr;
            }
        }
    }
}

// ---------------------------------------------------------------------------
// Heterogeneous fused launch: scatter blocks + L0a GEMM blocks + L0b blocks.
// Scatter is atomic-free (ticket from prep).
// ---------------------------------------------------------------------------
#define SCAT_BLKS 128
#define G0A_BLKS (8 * 2 * ((235 + 7) / 8))  // 480
#define G0B_BLKS (8 * 2 * ((157 + 7) / 8))  // 320

__global__ __launch_bounds__(512) void scatter_gemm0(
        const int* __restrict__ src, const int* __restrict__ dst,
        const int* __restrict__ rp, const int* __restrict__ tick,
        int* __restrict__ srcs,
        const _Float16* __restrict__ f0h, const _Float16* __restrict__ Wc0t,
        const _Float16* __restrict__ f1h, const _Float16* __restrict__ Wc1t,
        _Float16* __restrict__ featA, const float* __restrict__ al0,
        const float* __restrict__ ar0, const float* __restrict__ biasF,
        float* __restrict__ el, float* __restrict__ er) {
    __shared__ _Float16 Asl[128 * 32];
    __shared__ _Float16 Bsl[256 * 32];
    int bid = blockIdx.x;
    if (bid < SCAT_BLKS) {
        for (int t = bid * 512 + threadIdx.x; t < N_EDGES; t += SCAT_BLKS * 512) {
            srcs[rp[dst[t]] + tick[t]] = src[t];
        }
        return;
    }
    bid -= SCAT_BLKS;
    if (bid < G0A_BLKS) {
        gemm_tile(f0h, Wc0t, featA, al0, ar0, biasF, el, er,
                  30000, 256, 0, 235, bid, Asl, Bsl);
        return;
    }
    bid -= G0A_BLKS;
    gemm_tile(f1h, Wc1t, featA, al0, ar0, biasF + 512, el, er,
              20000, 128, 30000, 157, bid, Asl, Bsl);
}

// ---------------------------------------------------------------------------
// Standalone wide GEMM (layer 1)
// ---------------------------------------------------------------------------
__global__ __launch_bounds__(512) void gemm_mfma_wide(const _Float16* __restrict__ A,
                                                      const _Float16* __restrict__ Bt,
                                                      _Float16* __restrict__ Cb,
                                                      const float* __restrict__ al,
                                                      const float* __restrict__ ar,
                                                      float* __restrict__ el,
                                                      float* __restrict__ er,
                                                      int M, int K, int ytiles) {
    __shared__ _Float16 Asl[128 * 32];
    __shared__ _Float16 Bsl[256 * 32];
    gemm_tile(A, Bt, Cb, al, ar, nullptr, el, er, M, K, 0, ytiles,
              blockIdx.x, Asl, Bsl);
}

// ---------------------------------------------------------------------------
// Fused edge softmax + aggregation, one wave per block (proven structure,
// ~88 us = random-gather memory-path floor per r2-r4 ablations).
// ---------------------------------------------------------------------------
__global__ __launch_bounds__(64) void attn_agg(
        const int* __restrict__ rp, const int* __restrict__ srcs,
        const float* __restrict__ el, const float* __restrict__ er,
        const _Float16* __restrict__ feat, const float* __restrict__ bias,
        _Float16* __restrict__ out) {
    __shared__ float aS[592];   // [0..575] alpha (p*9+h), [576..583] inv, [584..591] m
    __shared__ int   sS[64];
    int lane = threadIdx.x;
    int n    = blockIdx.x;
    int s0 = rp[n], s1 = rp[n + 1];
    int deg = s1 - s0;
    float er8[8];
    {
        f32x4 a = *(const f32x4*)(er + (size_t)n * 8);
        f32x4 b = *(const f32x4*)(er + (size_t)n * 8 + 4);
        er8[0]=a[0]; er8[1]=a[1]; er8[2]=a[2]; er8[3]=a[3];
        er8[4]=b[0]; er8[5]=b[1]; er8[6]=b[2]; er8[7]=b[3];
    }
    bool fast = (deg <= 64);
    if (fast) {
        bool act = lane < deg;
        int sp = act ? srcs[s0 + lane] : 0;
        sS[lane] = sp;
        f32x4 ea = {0.f,0.f,0.f,0.f}, eb = {0.f,0.f,0.f,0.f};
        if (act) {
            ea = *(const f32x4*)(el + (size_t)sp * 8);
            eb = *(const f32x4*)(el + (size_t)sp * 8 + 4);
        }
        float e8[8] = {ea[0],ea[1],ea[2],ea[3],eb[0],eb[1],eb[2],eb[3]};
#pragma unroll
        for (int h = 0; h < 8; h++) {
            float e = e8[h] + er8[h];
            e = e > 0.f ? e : 0.2f * e;
            e8[h] = act ? e : -1e30f;
        }
#pragma unroll
        for (int h = 0; h < 8; h++) {
            float mm = e8[h];
#pragma unroll
            for (int mk = 1; mk < 64; mk <<= 1) mm = fmaxf(mm, __shfl_xor(mm, mk));
            float pv = act ? __expf(e8[h] - mm) : 0.f;
            float ss = pv;
#pragma unroll
            for (int mk = 1; mk < 64; mk <<= 1) ss += __shfl_xor(ss, mk);
            aS[lane * 9 + h] = pv * (1.f / fmaxf(ss, 1e-9f));  // pre-scaled alpha
        }
    } else {
        float m8[8], s8[8];
#pragma unroll
        for (int h = 0; h < 8; h++) { m8[h] = -1e30f; s8[h] = 0.f; }
        for (int base = s0; base < s1; base += 64) {
            bool act = base + lane < s1;
            int sp = act ? srcs[base + lane] : 0;
            f32x4 ea = {0.f,0.f,0.f,0.f}, eb = {0.f,0.f,0.f,0.f};
            if (act) {
                ea = *(const f32x4*)(el + (size_t)sp * 8);
                eb = *(const f32x4*)(el + (size_t)sp * 8 + 4);
            }
            float ev[8] = {ea[0],ea[1],ea[2],ea[3],eb[0],eb[1],eb[2],eb[3]};
#pragma unroll
            for (int h = 0; h < 8; h++) {
                float e = ev[h] + er8[h];
                e = e > 0.f ? e : 0.2f * e;
                e = act ? e : -1e30f;
                float cm = e;
#pragma unroll
                for (int mk = 1; mk < 64; mk <<= 1) cm = fmaxf(cm, __shfl_xor(cm, mk));
                float nm = fmaxf(m8[h], cm);
                float pv = act ? __expf(e - nm) : 0.f;
#pragma unroll
                for (int mk = 1; mk < 64; mk <<= 1) pv += __shfl_xor(pv, mk);
                s8[h] = s8[h] * __expf(m8[h] - nm) + pv;
                m8[h] = nm;
            }
        }
        if (lane == 0) {
#pragma unroll
            for (int h = 0; h < 8; h++) {
                aS[576 + h] = 1.f / fmaxf(s8[h], 1e-9f);
                aS[584 + h] = m8[h];
            }
        }
    }
    // wave-private LDS handoff (lockstep wave + compiler lgkmcnt ordering)
    __builtin_amdgcn_wave_barrier();
    int hh = lane >> 3, d0 = (lane & 7) * 8;   // lane*8 = hh*64 + d0
    h8v z = {(_Float16)0, (_Float16)0, (_Float16)0, (_Float16)0,
             (_Float16)0, (_Float16)0, (_Float16)0, (_Float16)0};
    h8v acc0 = z, acc1 = z, acc2 = z, acc3 = z;
    const _Float16* colbase = feat + hh * 64 + d0;
    if (fast) {
        int p = 0;
        for (; p + 4 <= deg; p += 4) {
            int spa = sS[p],     spb = sS[p + 1];
            int spc = sS[p + 2], spd = sS[p + 3];
            _Float16 aa = (_Float16)aS[p * 9 + hh];
            _Float16 ab = (_Float16)aS[(p + 1) * 9 + hh];
            _Float16 ac = (_Float16)aS[(p + 2) * 9 + hh];
            _Float16 ad = (_Float16)aS[(p + 3) * 9 + hh];
            h8v fa = *(const h8v*)(colbase + (size_t)spa * HD);
            h8v fb = *(const h8v*)(colbase + (size_t)spb * HD);
            h8v fc = *(const h8v*)(colbase + (size_t)spc * HD);
            h8v fd = *(const h8v*)(colbase + (size_t)spd * HD);
            h8v a8a = {aa, aa, aa, aa, aa, aa, aa, aa};
            h8v a8b = {ab, ab, ab, ab, ab, ab, ab, ab};
            h8v a8c = {ac, ac, ac, ac, ac, ac, ac, ac};
            h8v a8d = {ad, ad, ad, ad, ad, ad, ad, ad};
            acc0 += a8a * fa;
            acc1 += a8b * fb;
            acc2 += a8c * fc;
            acc3 += a8d * fd;
        }
        for (; p < deg; p++) {
            int sp = sS[p];
            _Float16 ah = (_Float16)aS[p * 9 + hh];
            h8v a8 = {ah, ah, ah, ah, ah, ah, ah, ah};
            h8v f = *(const h8v*)(colbase + (size_t)sp * HD);
            acc0 += a8 * f;
        }
    } else {
        float inv_l = aS[576 + hh];
        float m_l   = aS[584 + hh];
        float ern_l = er[(size_t)n * 8 + hh];
        for (int p = s0; p < s1; p++) {
            int sp = srcs[p];
            float e = el[(size_t)sp * 8 + hh] + ern_l;
            e = e > 0.f ? e : 0.2f * e;
            _Float16 ah = (_Float16)(__expf(e - m_l) * inv_l);
            h8v a8 = {ah, ah, ah, ah, ah, ah, ah, ah};
            h8v f = *(const h8v*)(colbase + (size_t)sp * HD);
            acc0 += a8 * f;
        }
    }
    acc0 += acc1; acc2 += acc3; acc0 += acc2;
    float4 b0v = *(const float4*)(bias + lane * 8);
    float4 b1v = *(const float4*)(bias + lane * 8 + 4);
    float bb[8] = {b0v.x,b0v.y,b0v.z,b0v.w,b1v.x,b1v.y,b1v.z,b1v.w};
    h8v o;
#pragma unroll
    for (int j = 0; j < 8; j++) {
        float x = (float)acc0[j] + bb[j];
        x = x > 0.f ? x : __expf(x) - 1.f;
        o[j] = (_Float16)x;
    }
    *(h8v*)(out + (size_t)n * HD + lane * 8) = o;
}

// ---------------------------------------------------------------------------
// Layer-2 variant: softmax+aggregation + fused [512->10] W2 projection.
// W2hT loaded at the EPILOGUE (r9-proven): preloading it (r11) cost VGPR
// 32->48 and dropped occupancy 79->52% — worse than the latency it hid.
// ---------------------------------------------------------------------------
__global__ __launch_bounds__(64) void attn_agg_l2(
        const int* __restrict__ rp, const int* __restrict__ srcs,
        const float* __restrict__ el, const float* __restrict__ er,
        const _Float16* __restrict__ feat, const float* __restrict__ bias,
        const _Float16* __restrict__ W2hT, const float* __restrict__ al2,
        const float* __restrict__ ar2, float* __restrict__ feat2,
        float* __restrict__ el2, float* __restrict__ er2) {
    __shared__ float aS[592];
    __shared__ int   sS[64];
    int lane = threadIdx.x;
    int n    = blockIdx.x;
    int s0 = rp[n], s1 = rp[n + 1];
    int deg = s1 - s0;
    float er8[8];
    {
        f32x4 a = *(const f32x4*)(er + (size_t)n * 8);
        f32x4 b = *(const f32x4*)(er + (size_t)n * 8 + 4);
        er8[0]=a[0]; er8[1]=a[1]; er8[2]=a[2]; er8[3]=a[3];
        er8[4]=b[0]; er8[5]=b[1]; er8[6]=b[2]; er8[7]=b[3];
    }
    bool fast = (deg <= 64);
    if (fast) {
        bool act = lane < deg;
        int sp = act ? srcs[s0 + lane] : 0;
        sS[lane] = sp;
        f32x4 ea = {0.f,0.f,0.f,0.f}, eb = {0.f,0.f,0.f,0.f};
        if (act) {
            ea = *(const f32x4*)(el + (size_t)sp * 8);
            eb = *(const f32x4*)(el + (size_t)sp * 8 + 4);
        }
        float e8[8] = {ea[0],ea[1],ea[2],ea[3],eb[0],eb[1],eb[2],eb[3]};
#pragma unroll
        for (int h = 0; h < 8; h++) {
            float e = e8[h] + er8[h];
            e = e > 0.f ? e : 0.2f * e;
            e8[h] = act ? e : -1e30f;
        }
#pragma unroll
        for (int h = 0; h < 8; h++) {
            float mm = e8[h];
#pragma unroll
            for (int mk = 1; mk < 64; mk <<= 1) mm = fmaxf(mm, __shfl_xor(mm, mk));
            float pv = act ? __expf(e8[h] - mm) : 0.f;
            float ss = pv;
#pragma unroll
            for (int mk = 1; mk < 64; mk <<= 1) ss += __shfl_xor(ss, mk);
            aS[lane * 9 + h] = pv * (1.f / fmaxf(ss, 1e-9f));
        }
    } else {
        float m8[8], s8[8];
#pragma unroll
        for (int h = 0; h < 8; h++) { m8[h] = -1e30f; s8[h] = 0.f; }
        for (int base = s0; base < s1; base += 64) {
            bool act = base + lane < s1;
            int sp = act ? srcs[base + lane] : 0;
            f32x4 ea = {0.f,0.f,0.f,0.f}, eb = {0.f,0.f,0.f,0.f};
            if (act) {
                ea = *(const f32x4*)(el + (size_t)sp * 8);
                eb = *(const f32x4*)(el + (size_t)sp * 8 + 4);
            }
            float ev[8] = {ea[0],ea[1],ea[2],ea[3],eb[0],eb[1],eb[2],eb[3]};
#pragma unroll
            for (int h = 0; h < 8; h++) {
                float e = ev[h] + er8[h];
                e = e > 0.f ? e : 0.2f * e;
                e = act ? e : -1e30f;
                float cm = e;
#pragma unroll
                for (int mk = 1; mk < 64; mk <<= 1) cm = fmaxf(cm, __shfl_xor(cm, mk));
                float nm = fmaxf(m8[h], cm);
                float pv = act ? __expf(e - nm) : 0.f;
#pragma unroll
                for (int mk = 1; mk < 64; mk <<= 1) pv += __shfl_xor(pv, mk);
                s8[h] = s8[h] * __expf(m8[h] - nm) + pv;
                m8[h] = nm;
            }
        }
        if (lane == 0) {
#pragma unroll
            for (int h = 0; h < 8; h++) {
                aS[576 + h] = 1.f / fmaxf(s8[h], 1e-9f);
                aS[584 + h] = m8[h];
            }
        }
    }
    __builtin_amdgcn_wave_barrier();
    int hh = lane >> 3, d0 = (lane & 7) * 8;
    h8v z = {(_Float16)0, (_Float16)0, (_Float16)0, (_Float16)0,
             (_Float16)0, (_Float16)0, (_Float16)0, (_Float16)0};
    h8v acc0 = z, acc1 = z, acc2 = z, acc3 = z;
    const _Float16* colbase = feat + hh * 64 + d0;
    if (fast) {
        int p = 0;
        for (; p + 4 <= deg; p += 4) {
            int spa = sS[p],     spb = sS[p + 1];
            int spc = sS[p + 2], spd = sS[p + 3];
            _Float16 aa = (_Float16)aS[p * 9 + hh];
            _Float16 ab = (_Float16)aS[(p + 1) * 9 + hh];
            _Float16 ac = (_Float16)aS[(p + 2) * 9 + hh];
            _Float16 ad = (_Float16)aS[(p + 3) * 9 + hh];
            h8v fa = *(const h8v*)(colbase + (size_t)spa * HD);
            h8v fb = *(const h8v*)(colbase + (size_t)spb * HD);
            h8v fc = *(const h8v*)(colbase + (size_t)spc * HD);
            h8v fd = *(const h8v*)(colbase + (size_t)spd * HD);
            h8v a8a = {aa, aa, aa, aa, aa, aa, aa, aa};
            h8v a8b = {ab, ab, ab, ab, ab, ab, ab, ab};
            h8v a8c = {ac, ac, ac, ac, ac, ac, ac, ac};
            h8v a8d = {ad, ad, ad, ad, ad, ad, ad, ad};
            acc0 += a8a * fa;
            acc1 += a8b * fb;
            acc2 += a8c * fc;
            acc3 += a8d * fd;
        }
        for (; p < deg; p++) {
            int sp = sS[p];
            _Float16 ah = (_Float16)aS[p * 9 + hh];
            h8v a8 = {ah, ah, ah, ah, ah, ah, ah, ah};
            h8v f = *(const h8v*)(colbase + (size_t)sp * HD);
            acc0 += a8 * f;
        }
    } else {
        float inv_l = aS[576 + hh];
        float m_l   = aS[584 + hh];
        float ern_l = er[(size_t)n * 8 + hh];
        for (int p = s0; p < s1; p++) {
            int sp = srcs[p];
            float e = el[(size_t)sp * 8 + hh] + ern_l;
            e = e > 0.f ? e : 0.2f * e;
            _Float16 ah = (_Float16)(__expf(e - m_l) * inv_l);
            h8v a8 = {ah, ah, ah, ah, ah, ah, ah, ah};
            h8v f = *(const h8v*)(colbase + (size_t)sp * HD);
            acc0 += a8 * f;
        }
    }
    acc0 += acc1; acc2 += acc3; acc0 += acc2;
    float4 b0v = *(const float4*)(bias + lane * 8);
    float4 b1v = *(const float4*)(bias + lane * 8 + 4);
    float bb[8] = {b0v.x,b0v.y,b0v.z,b0v.w,b1v.x,b1v.y,b1v.z,b1v.w};
    float x[8];
#pragma unroll
    for (int j = 0; j < 8; j++) {
        float v = (float)acc0[j] + bb[j];
        x[j] = v > 0.f ? v : __expf(v) - 1.f;     // ELU in f32 (layer-1 act)
    }
    // fused [512->10] projection: lane owns j-cols lane*8..lane*8+7.
    float s[NCLS];
    const _Float16* w2base = W2hT + lane * 8;
#if __has_builtin(__builtin_amdgcn_fdot2)
    h2v xh[4];
#pragma unroll
    for (int j = 0; j < 4; j++)
        xh[j] = (h2v){(_Float16)x[2 * j], (_Float16)x[2 * j + 1]};
#pragma unroll
    for (int c = 0; c < NCLS; c++) {
        h8v w = *(const h8v*)(w2base + (size_t)c * 512);
        float acc = 0.f;
#pragma unroll
        for (int jp = 0; jp < 4; jp++) {
            h2v wp = (h2v){w[2 * jp], w[2 * jp + 1]};
            acc = __builtin_amdgcn_fdot2(xh[jp], wp, acc, false);
        }
        s[c] = acc;
    }
#else
#pragma unroll
    for (int c = 0; c < NCLS; c++) {
        h8v w = *(const h8v*)(w2base + (size_t)c * 512);
        float acc = 0.f;
#pragma unroll
        for (int j = 0; j < 8; j++) acc += x[j] * (float)w[j];
        s[c] = acc;
    }
#endif
#pragma unroll
    for (int c = 0; c < NCLS; c++)
#pragma unroll
        for (int mk = 1; mk < 64; mk <<= 1) s[c] += __shfl_xor(s[c], mk);
    if (lane == 0) {
        float e1 = 0.f, e2 = 0.f;
#pragma unroll
        for (int c = 0; c < NCLS; c++) { e1 += s[c] * al2[c]; e2 += s[c] * ar2[c]; }
        el2[n] = e1; er2[n] = e2;
#pragma unroll
        for (int c = 0; c < NCLS; c++) feat2[(size_t)n * F2S + c] = s[c];
    }
}

// ---------------------------------------------------------------------------
// layer 2 fused softmax+aggregation (H=1, D=10), one wave per block.
// feat2 rows padded to stride 12 -> 3x f32x4 vector loads.
// ---------------------------------------------------------------------------
__global__ __launch_bounds__(64) void attn2_agg2(
        const int* __restrict__ rp, const int* __restrict__ srcs,
        const float* __restrict__ el, const float* __restrict__ er,
        const float* __restrict__ feat2, const float* __restrict__ b2,
        float* __restrict__ out) {
    int lane = threadIdx.x;
    int n = blockIdx.x;
    int s0 = rp[n], s1 = rp[n + 1], deg = s1 - s0;
    float ern = er[n];
    float facc[NCLS];
#pragma unroll
    for (int c = 0; c < NCLS; c++) facc[c] = 0.f;
    if (deg <= 64) {
        bool act = lane < deg;
        int sp = act ? srcs[s0 + lane] : 0;
        float e = act ? el[sp] + ern : 0.f;
        e = e > 0.f ? e : 0.2f * e;
        if (!act) e = -1e30f;
        float mm = e;
#pragma unroll
        for (int mk = 1; mk < 64; mk <<= 1) mm = fmaxf(mm, __shfl_xor(mm, mk));
        float pv = act ? __expf(e - mm) : 0.f;
        float ss = pv;
#pragma unroll
        for (int mk = 1; mk < 64; mk <<= 1) ss += __shfl_xor(ss, mk);
        float a = pv / fmaxf(ss, 1e-9f);
        if (act) {
            const float* fr = feat2 + (size_t)sp * F2S;
            f32x4 fa = *(const f32x4*)fr;
            f32x4 fb = *(const f32x4*)(fr + 4);
            f32x4 fc = *(const f32x4*)(fr + 8);
            float fv[NCLS] = {fa[0],fa[1],fa[2],fa[3],fb[0],fb[1],fb[2],fb[3],fc[0],fc[1]};
#pragma unroll
            for (int c = 0; c < NCLS; c++) facc[c] = a * fv[c];
        }
    } else {
        float mm = -1e30f, ssum = 0.f;
        for (int base = s0; base < s1; base += 64) {
            bool act = base + lane < s1;
            int sp = act ? srcs[base + lane] : 0;
            float e = act ? el[sp] + ern : 0.f;
            e = e > 0.f ? e : 0.2f * e;
            if (!act) e = -1e30f;
            float cm = e;
#pragma unroll
            for (int mk = 1; mk < 64; mk <<= 1) cm = fmaxf(cm, __shfl_xor(cm, mk));
            float nm = fmaxf(mm, cm);
            float pv = act ? __expf(e - nm) : 0.f;
#pragma unroll
            for (int mk = 1; mk < 64; mk <<= 1) pv += __shfl_xor(pv, mk);
            ssum = ssum * __expf(mm - nm) + pv;
            mm = nm;
        }
        float inv = 1.f / fmaxf(ssum, 1e-9f);
        for (int base = s0; base < s1; base += 64) {
            bool act = base + lane < s1;
            int sp = act ? srcs[base + lane] : 0;
            float e = act ? el[sp] + ern : 0.f;
            e = e > 0.f ? e : 0.2f * e;
            float a = act ? __expf(e - mm) * inv : 0.f;
            if (act) {
                const float* fr = feat2 + (size_t)sp * F2S;
                f32x4 fa = *(const f32x4*)fr;
                f32x4 fb = *(const f32x4*)(fr + 4);
                f32x4 fc = *(const f32x4*)(fr + 8);
                float fv[NCLS] = {fa[0],fa[1],fa[2],fa[3],fb[0],fb[1],fb[2],fb[3],fc[0],fc[1]};
#pragma unroll
                for (int c = 0; c < NCLS; c++) facc[c] += a * fv[c];
            }
        }
    }
#pragma unroll
    for (int c = 0; c < NCLS; c++)
#pragma unroll
        for (int mk = 1; mk < 64; mk <<= 1) facc[c] += __shfl_xor(facc[c], mk);
    if (lane == 0) {
#pragma unroll
        for (int c = 0; c < NCLS; c++) out[(size_t)n * NCLS + c] = facc[c] + b2[c];
    }
}

// ---------------------------------------------------------------------------
extern "C" void kernel_launch(void* const* d_in, const int* in_sizes, int n_in,
                              void* d_out, int out_size, void* d_ws, size_t ws_size,
                              hipStream_t stream) {
    const float* feat0 = (const float*)d_in[0];
    const float* feat1 = (const float*)d_in[1];
    const float* fc0_w = (const float*)d_in[2];
    const float* fc0_b = (const float*)d_in[3];
    const float* fc1_w = (const float*)d_in[4];
    const float* fc1_b = (const float*)d_in[5];
    const float* W0    = (const float*)d_in[6];
    const float* al0   = (const float*)d_in[7];
    const float* ar0   = (const float*)d_in[8];
    const float* b0    = (const float*)d_in[9];
    const float* W1    = (const float*)d_in[10];
    const float* al1   = (const float*)d_in[11];
    const float* ar1   = (const float*)d_in[12];
    const float* b1    = (const float*)d_in[13];
    const float* W2    = (const float*)d_in[14];
    const float* al2   = (const float*)d_in[15];
    const float* ar2   = (const float*)d_in[16];
    const float* b2    = (const float*)d_in[17];
    const int* eidx    = (const int*)d_in[18];
    const int* src = eidx;
    const int* dst = eidx + N_EDGES;
    float* out = (float*)d_out;

    char* ws = (char*)d_ws;
    size_t off = 0;
    auto alloc = [&](size_t bytes) { size_t o = off; off = (off + bytes + 255) & ~(size_t)255; return o; };

    _Float16* featA = (_Float16*)(ws + alloc((size_t)M_PAD * HD * 2));
    _Float16* aggh  = (_Float16*)(ws + alloc((size_t)M_PAD * HD * 2));
    _Float16* f0h   = (_Float16*)(ws + alloc((size_t)F0ROWS * 256 * 2));
    _Float16* f1h   = (_Float16*)(ws + alloc((size_t)F1ROWS * 128 * 2));
    float*    feat2 = (float*)(ws + alloc((size_t)N_NODES * F2S * 4));
    float*    el    = (float*)(ws + alloc((size_t)N_NODES * HEADS * 4));
    float*    er    = (float*)(ws + alloc((size_t)N_NODES * HEADS * 4));
    float*    el2   = (float*)(ws + alloc((size_t)N_NODES * 4));
    float*    er2   = (float*)(ws + alloc((size_t)N_NODES * 4));
    float*    biasF = (float*)(ws + alloc(1024 * 4));
    int*      cnt   = (int*)  (ws + alloc((size_t)N_NODES * 4));
    int*      rp    = (int*)  (ws + alloc((size_t)(N_NODES + 1) * 4));
    int*      tick  = (int*)  (ws + alloc((size_t)N_EDGES * 4));
    int*      srcs  = (int*)  (ws + alloc((size_t)N_EDGES * 4));
    int*      part  = (int*)  (ws + alloc(1024));
    _Float16* Wc0t  = (_Float16*)(ws + alloc(512 * 256 * 2));
    _Float16* Wc1t  = (_Float16*)(ws + alloc(512 * 128 * 2));
    _Float16* W1t   = (_Float16*)(ws + alloc(512 * 512 * 2));
    _Float16* W2hT  = (_Float16*)(ws + alloc(5120 * 2));

    // --- cnt zero, then prep (weight folds + casts + count/ticket fused) ---
    hipMemsetAsync(cnt, 0, N_NODES * sizeof(int), stream);
    prep<<<(PREP_TOTAL + 255) / 256, 256, 0, stream>>>(
        feat0, feat1, fc0_w, fc0_b, fc1_w, fc1_b, W0, W1, W2, dst,
        f0h, f1h, Wc0t, Wc1t, W1t, W2hT, biasF, cnt, tick);

    // --- CSR scan ---
    scan_part<<<NBLK_SCAN, 256, 0, stream>>>(cnt, part);
    scan_offs<<<1, 256, 0, stream>>>(part);
    scan_apply<<<NBLK_SCAN, 256, 0, stream>>>(cnt, part, rp);

    // --- fused: atomic-free scatter + layer-0 GEMMs (one launch) ---
    scatter_gemm0<<<SCAT_BLKS + G0A_BLKS + G0B_BLKS, 512, 0, stream>>>(
        src, dst, rp, tick, srcs, f0h, Wc0t, f1h, Wc1t, featA, al0, ar0, biasF, el, er);

    attn_agg<<<N_NODES, 64, 0, stream>>>(rp, srcs, el, er, featA, b0, aggh);

    // --- layer 1 ---
    int g1 = 8 * 2 * ((YTILES_L1 + 7) / 8);  // 784
    gemm_mfma_wide<<<g1, 512, 0, stream>>>(aggh, W1t, featA, al1, ar1, el, er,
                                           N_NODES, HD, YTILES_L1);

    // --- layer 1 attn + fused layer-2 projection ---
    attn_agg_l2<<<N_NODES, 64, 0, stream>>>(rp, srcs, el, er, featA, b1,
                                            W2hT, al2, ar2, feat2, el2, er2);

    // --- layer 2 softmax+agg ---
    attn2_agg2<<<N_NODES, 64, 0, stream>>>(rp, srcs, el2, er2, feat2, b2, out);
}